// Round 3
// baseline (870.044 us; speedup 1.0000x reference)
//
#include <hip/hip_runtime.h>
#include <hip/hip_bf16.h>

typedef unsigned short u16;
typedef __bf16 bf16x8 __attribute__((ext_vector_type(8)));
typedef float f32x4 __attribute__((ext_vector_type(4)));

static __device__ __forceinline__ float b2f(u16 x) {
    unsigned int u = ((unsigned int)x) << 16;
    float f; __builtin_memcpy(&f, &u, 4); return f;
}
static __device__ __forceinline__ float b2f_u32(unsigned int u) {
    float f; __builtin_memcpy(&f, &u, 4); return f;
}
static __device__ __forceinline__ u16 f2b(float f) {
    unsigned int u; __builtin_memcpy(&u, &f, 4);
    unsigned int lsb = (u >> 16) & 1u;
    u += 0x7fffu + lsb;
    return (u16)(u >> 16);
}

// async 16B global->LDS (wave-uniform LDS base + lane*16)
static __device__ __forceinline__ void gload16(const u16* g, u16* l) {
    __builtin_amdgcn_global_load_lds(
        (const __attribute__((address_space(1))) unsigned int*)g,
        (__attribute__((address_space(3))) unsigned int*)l, 16, 0, 0);
}

// ---------------- transpose+convert: src fp32 [R][C] -> dst bf16 [C][R] ----------------
__global__ __launch_bounds__(256) void transpose_f2b(const float* __restrict__ src,
                                                     u16* __restrict__ dst,
                                                     int R, int C) {
    __shared__ u16 tile[32][33];
    int c0 = blockIdx.x * 32, r0 = blockIdx.y * 32;
    int tx = threadIdx.x & 31, ty = threadIdx.x >> 5;
    for (int i = ty; i < 32; i += 8) {
        int r = r0 + i, c = c0 + tx;
        tile[i][tx] = (r < R && c < C) ? f2b(src[(long)r * C + c]) : (u16)0;
    }
    __syncthreads();
    for (int i = ty; i < 32; i += 8) {
        int c = c0 + i, r = r0 + tx;
        if (c < C && r < R) dst[(long)c * R + r] = tile[tx][i];
    }
}

// ---------------- concat 3 fp32 bias vectors of 1024 ----------------
__global__ __launch_bounds__(256) void concat3(const float* a, const float* b, const float* c,
                                               float* out) {
    int i = blockIdx.x * 256 + threadIdx.x;
    if (i < 1024) out[i] = a[i];
    else if (i < 2048) out[i] = b[i - 1024];
    else if (i < 3072) out[i] = c[i - 2048];
}

// ---------------- fp32 -> bf16 bulk convert ----------------
__global__ __launch_bounds__(256) void conv_f2b(const float* __restrict__ src,
                                                u16* __restrict__ dst, long n) {
    long i = ((long)blockIdx.x * 256 + threadIdx.x) * 4;
    if (i >= n) return;
    float4 f = *(const float4*)(src + i);
    ushort4 o;
    o.x = f2b(f.x); o.y = f2b(f.y); o.z = f2b(f.z); o.w = f2b(f.w);
    *(ushort4*)(dst + i) = o;
}

// ---------------- 256x256 8-phase bt-GEMM (T2 swizzle + T3/T4 counted vmcnt + T5) ----
// See round-1 notes; schedule verified (passed, absmax unchanged).
__global__ __launch_bounds__(512, 1) void gemm_bt256(
    const u16* __restrict__ A, const u16* __restrict__ B,
    const float* __restrict__ bias, u16* __restrict__ C,
    int M, int N, int K, int lda, int ldb, int ldc, int relu, int nbx) {
    __shared__ __align__(16) u16 lds[2][4][8192];

    int nwg = gridDim.x;
    int id = blockIdx.x;
    int swz = (id & 7) * (nwg >> 3) + (id >> 3);   // nwg % 8 == 0 at all call sites
    int bx = swz % nbx, by = swz / nbx;
    long m0 = (long)by * 256, n0 = (long)bx * 256;

    int tid = threadIdx.x, lane = tid & 63, wave = tid >> 6;
    int lrow = lane & 15, quad = lane >> 4;
    int wm2 = wave >> 2;        // M-half of wave (interleaved 16-row slabs)
    int wn2 = wave & 3;         // N-group of wave (interleaved 16-col slabs)

    int laneRd = (lrow * 64 + quad * 16) ^ (((lrow >> 3) & 1) << 5);
    int Sl = (lane * 16) ^ (((lane >> 5) & 1) << 5);
    int wr = (Sl >> 6) & 15;
    int wb = Sl & 63;

    f32x4 acc[8][4];
#pragma unroll
    for (int i = 0; i < 8; i++)
#pragma unroll
        for (int j = 0; j < 4; j++) acc[i][j] = (f32x4){0.f, 0.f, 0.f, 0.f};
    bf16x8 af[4][2], bfr[2][2];

#define STAGE_HT(nb, ht, kt) do {                                              \
    const char* _gb = ((ht) < 2)                                               \
        ? (const char*)(A + (m0 + (ht) * 128) * lda)                           \
        : (const char*)(B + (n0 + ((ht) - 2) * 128) * ldb);                    \
    long _ld = (long)(((ht) < 2) ? lda : ldb) * 2;                             \
    _Pragma("unroll")                                                          \
    for (int j = 0; j < 2; j++) {                                              \
        int sub = j * 8 + wave;                                                \
        int srow = (sub >> 1) * 16 + wr;                                       \
        int scolb = (sub & 1) * 64 + wb;                                       \
        gload16((const u16*)(_gb + (long)srow * _ld + (long)(kt) * 128 + scolb),\
                &lds[nb][ht][sub << 9]);                                       \
    }                                                                          \
} while (0)

#define DSLOAD_A(qm) do {                                                      \
    const char* _p = _ab + ((qm) << 14);                                       \
    _Pragma("unroll") for (int mi = 0; mi < 4; mi++)                           \
    _Pragma("unroll") for (int kk = 0; kk < 2; kk++)                           \
        af[mi][kk] = *(const bf16x8*)(_p + ((mi * 4 + kk) << 10));             \
} while (0)

#define DSLOAD_B(qn) do {                                                      \
    const char* _p = _bb + ((qn) << 14);                                       \
    _Pragma("unroll") for (int ni = 0; ni < 2; ni++)                           \
    _Pragma("unroll") for (int kk = 0; kk < 2; kk++)                           \
        bfr[ni][kk] = *(const bf16x8*)(_p + ((ni * 8 + kk) << 10));            \
} while (0)

#define DOMFMA(qm, qn) do {                                                    \
    __builtin_amdgcn_s_setprio(1);                                             \
    _Pragma("unroll") for (int mi = 0; mi < 4; mi++)                           \
    _Pragma("unroll") for (int ni = 0; ni < 2; ni++)                           \
    _Pragma("unroll") for (int kk = 0; kk < 2; kk++)                           \
        acc[(qm) * 4 + mi][(qn) * 2 + ni] =                                    \
            __builtin_amdgcn_mfma_f32_16x16x32_bf16(                           \
                af[mi][kk], bfr[ni][kk], acc[(qm) * 4 + mi][(qn) * 2 + ni],    \
                0, 0, 0);                                                      \
    __builtin_amdgcn_s_setprio(0);                                             \
} while (0)

#define MIDBAR()  do { __builtin_amdgcn_s_barrier(); __builtin_amdgcn_sched_barrier(0); } while (0)
#define ENDBAR()  do { __builtin_amdgcn_sched_barrier(0); __builtin_amdgcn_s_barrier(); } while (0)

    int NT = K >> 6;
    STAGE_HT(0, 0, 0);
    STAGE_HT(0, 2, 0);
    STAGE_HT(0, 1, 0);
    STAGE_HT(0, 3, 0);

    for (int t = 0; t < NT - 1; t++) {
        int cur = t & 1, nxt = cur ^ 1;
        const char* _ab = (const char*)&lds[cur][0][0] + (wm2 << 11) + laneRd;
        const char* _bb = (const char*)&lds[cur][2][0] + (wn2 << 11) + laneRd;
        STAGE_HT(nxt, 0, t + 1);
        asm volatile("s_waitcnt vmcnt(6)" ::: "memory");
        MIDBAR();
        DSLOAD_A(0); DSLOAD_B(0); DOMFMA(0, 0);
        ENDBAR();
        STAGE_HT(nxt, 2, t + 1);
        asm volatile("s_waitcnt vmcnt(6)" ::: "memory");
        MIDBAR();
        DSLOAD_A(1); DOMFMA(1, 0);
        ENDBAR();
        STAGE_HT(nxt, 1, t + 1);
        asm volatile("s_waitcnt vmcnt(6)" ::: "memory");
        MIDBAR();
        DSLOAD_B(1); DOMFMA(1, 1);
        ENDBAR();
        STAGE_HT(nxt, 3, t + 1);
        MIDBAR();
        DSLOAD_A(0); DOMFMA(0, 1);
        ENDBAR();
    }
    {   // tail tile: drain 4 -> 2 -> 0
        int cur = (NT - 1) & 1;
        const char* _ab = (const char*)&lds[cur][0][0] + (wm2 << 11) + laneRd;
        const char* _bb = (const char*)&lds[cur][2][0] + (wn2 << 11) + laneRd;
        asm volatile("s_waitcnt vmcnt(4)" ::: "memory");
        MIDBAR();
        DSLOAD_A(0); DSLOAD_B(0); DOMFMA(0, 0);
        ENDBAR();
        asm volatile("s_waitcnt vmcnt(2)" ::: "memory");
        MIDBAR();
        DSLOAD_A(1); DOMFMA(1, 0);
        ENDBAR();
        asm volatile("s_waitcnt vmcnt(0)" ::: "memory");
        MIDBAR();
        DSLOAD_B(1); DOMFMA(1, 1);
        ENDBAR();
        DSLOAD_A(0); DOMFMA(0, 1);
    }

#pragma unroll
    for (int mg = 0; mg < 8; mg++) {
        long row0 = m0 + (long)(((mg >> 2) * 8 + (mg & 3) * 2 + wm2) * 16 + quad * 4);
#pragma unroll
        for (int ng = 0; ng < 4; ng++) {
            long col = n0 + ((ng >> 1) * 8 + (ng & 1) * 4 + wn2) * 16 + lrow;
            float bv = bias ? bias[col] : 0.f;
#pragma unroll
            for (int r = 0; r < 4; r++) {
                float v = acc[mg][ng][r] + bv;
                if (relu) v = fmaxf(v, 0.f);
                C[(row0 + r) * ldc + col] = f2b(v);
            }
        }
    }
#undef STAGE_HT
#undef DSLOAD_A
#undef DSLOAD_B
#undef DOMFMA
}

// ---------------- 128x256 2-phase counted-vmcnt bt-GEMM (for N=1024 shapes) --------
// Same template, 3 half-tiles per K-tile (A0,B0,B1), 2 phases x 16 MFMA.
// Steady-state in-flight arithmetic: issue stream per tile = A0@P1, B0,B1@P2
// (2 gload16/thread each). P1 after issuing A0(t+1): outstanding {A0(t),B0(t),
// B1(t),A0(t+1)}=8, need A0(t),B0(t) -> vmcnt(4). P2 after issuing B0/B1(t+1):
// outstanding {B1(t),A0(t+1),B0(t+1),B1(t+1)}=8, need B1(t) -> vmcnt(6).
// Tail drains 2 -> 0. Grid 256 blocks -> full CU coverage (vs 128 for 256^2).
__global__ __launch_bounds__(512, 1) void gemm_btn(
    const u16* __restrict__ A, const u16* __restrict__ B,
    const float* __restrict__ bias, u16* __restrict__ C,
    int K, int lda, int ldb, int ldc, int relu, int nbx) {
    __shared__ __align__(16) u16 lds[2][3][8192];

    int nwg = gridDim.x;
    int id = blockIdx.x;
    int swz = (id & 7) * (nwg >> 3) + (id >> 3);
    int bx = swz % nbx, by = swz / nbx;
    long m0 = (long)by * 128, n0 = (long)bx * 256;

    int tid = threadIdx.x, lane = tid & 63, wave = tid >> 6;
    int lrow = lane & 15, quad = lane >> 4;
    int wm2 = wave >> 2;
    int wn2 = wave & 3;

    int laneRd = (lrow * 64 + quad * 16) ^ (((lrow >> 3) & 1) << 5);
    int Sl = (lane * 16) ^ (((lane >> 5) & 1) << 5);
    int wr = (Sl >> 6) & 15;
    int wb = Sl & 63;

    f32x4 acc[4][4];
#pragma unroll
    for (int i = 0; i < 4; i++)
#pragma unroll
        for (int j = 0; j < 4; j++) acc[i][j] = (f32x4){0.f, 0.f, 0.f, 0.f};
    bf16x8 af[4][2], bfr[2][2];

#define STAGE_HT(nb, ht, kt) do {                                              \
    const char* _gb = ((ht) == 0)                                              \
        ? (const char*)(A + m0 * lda)                                          \
        : (const char*)(B + (n0 + ((ht) - 1) * 128) * ldb);                    \
    long _ld = (long)(((ht) == 0) ? lda : ldb) * 2;                            \
    _Pragma("unroll")                                                          \
    for (int j = 0; j < 2; j++) {                                              \
        int sub = j * 8 + wave;                                                \
        int srow = (sub >> 1) * 16 + wr;                                       \
        int scolb = (sub & 1) * 64 + wb;                                       \
        gload16((const u16*)(_gb + (long)srow * _ld + (long)(kt) * 128 + scolb),\
                &lds[nb][ht][sub << 9]);                                       \
    }                                                                          \
} while (0)

#define DSLOAD_A() do {                                                        \
    _Pragma("unroll") for (int mi = 0; mi < 4; mi++)                           \
    _Pragma("unroll") for (int kk = 0; kk < 2; kk++)                           \
        af[mi][kk] = *(const bf16x8*)(_ab + ((mi * 4 + kk) << 10));            \
} while (0)

#define DSLOAD_B(qn) do {                                                      \
    const char* _p = _b0 + (qn) * 16384;                                       \
    _Pragma("unroll") for (int ni = 0; ni < 2; ni++)                           \
    _Pragma("unroll") for (int kk = 0; kk < 2; kk++)                           \
        bfr[ni][kk] = *(const bf16x8*)(_p + ((ni * 8 + kk) << 10));            \
} while (0)

#define DOMFMA(qn) do {                                                        \
    __builtin_amdgcn_s_setprio(1);                                             \
    _Pragma("unroll") for (int mi = 0; mi < 4; mi++)                           \
    _Pragma("unroll") for (int ni = 0; ni < 2; ni++)                           \
    _Pragma("unroll") for (int kk = 0; kk < 2; kk++)                           \
        acc[mi][(qn) * 2 + ni] =                                               \
            __builtin_amdgcn_mfma_f32_16x16x32_bf16(                           \
                af[mi][kk], bfr[ni][kk], acc[mi][(qn) * 2 + ni], 0, 0, 0);     \
    __builtin_amdgcn_s_setprio(0);                                             \
} while (0)

    int NT = K >> 6;
    STAGE_HT(0, 0, 0);
    STAGE_HT(0, 1, 0);
    STAGE_HT(0, 2, 0);

    for (int t = 0; t < NT - 1; t++) {
        int cur = t & 1, nxt = cur ^ 1;
        const char* _ab = (const char*)&lds[cur][0][0] + (wm2 << 11) + laneRd;
        const char* _b0 = (const char*)&lds[cur][1][0] + (wn2 << 11) + laneRd;
        // P1: cols 0-1 (B0); stage T+1.A0
        STAGE_HT(nxt, 0, t + 1);
        asm volatile("s_waitcnt vmcnt(4)" ::: "memory");
        MIDBAR();
        DSLOAD_A(); DSLOAD_B(0); DOMFMA(0);
        ENDBAR();
        // P2: cols 2-3 (B1); stage T+1.B0,B1
        STAGE_HT(nxt, 1, t + 1);
        STAGE_HT(nxt, 2, t + 1);
        asm volatile("s_waitcnt vmcnt(6)" ::: "memory");
        MIDBAR();
        DSLOAD_B(1); DOMFMA(1);
        ENDBAR();
    }
    {   // tail tile: drain 2 -> 0
        int cur = (NT - 1) & 1;
        const char* _ab = (const char*)&lds[cur][0][0] + (wm2 << 11) + laneRd;
        const char* _b0 = (const char*)&lds[cur][1][0] + (wn2 << 11) + laneRd;
        asm volatile("s_waitcnt vmcnt(2)" ::: "memory");
        MIDBAR();
        DSLOAD_A(); DSLOAD_B(0); DOMFMA(0);
        ENDBAR();
        asm volatile("s_waitcnt vmcnt(0)" ::: "memory");
        MIDBAR();
        DSLOAD_B(1); DOMFMA(1);
    }

#pragma unroll
    for (int mi = 0; mi < 4; mi++) {
        long row0 = m0 + (long)((mi * 2 + wm2) * 16 + quad * 4);
#pragma unroll
        for (int ng = 0; ng < 4; ng++) {
            long col = n0 + ((ng >> 1) * 8 + (ng & 1) * 4 + wn2) * 16 + lrow;
            float bv = bias ? bias[col] : 0.f;
#pragma unroll
            for (int r = 0; r < 4; r++) {
                float v = acc[mi][ng][r] + bv;
                if (relu) v = fmaxf(v, 0.f);
                C[(row0 + r) * ldc + col] = f2b(v);
            }
        }
    }
#undef STAGE_HT
#undef DSLOAD_A
#undef DSLOAD_B
#undef DOMFMA
#undef MIDBAR
#undef ENDBAR
}

// ---------------- extract v from qkv (bf16), transposed per head ----------------
__global__ __launch_bounds__(256) void split_v(const u16* __restrict__ qkv,
                                               u16* __restrict__ vT) {
    __shared__ u16 tile[32][33];
    int bh = blockIdx.z;
    int b = bh >> 4, h = bh & 15;
    int s0 = blockIdx.x * 32;
    int d0 = blockIdx.y * 32;
    int tx = threadIdx.x & 31, ty = threadIdx.x >> 5;
    for (int i = ty; i < 32; i += 8)
        tile[i][tx] = qkv[((long)(b * 512 + s0 + i)) * 3072 + 2048 + h * 64 + d0 + tx];
    __syncthreads();
    for (int i = ty; i < 32; i += 8)
        vT[((long)bh * 64 + d0 + i) * 512 + s0 + tx] = tile[tx][i];
}

// ---------------- fused attention: scores + mask + softmax + PV ----------------
// K and V are L2-resident after the XCD-aware decode -> no K LDS staging: QK^T
// B-operand fragments are read directly from global (same pattern PV uses).
// Only one barrier remains (Q tile + mask bits). s_p is wave-private; the
// compiler orders same-wave ds_write->ds_read dependencies.
__global__ __launch_bounds__(256) void attn_fused(
    const u16* __restrict__ qkv, const u16* __restrict__ vT,
    const int* __restrict__ mask, float* __restrict__ attnOut,
    u16* __restrict__ ctx) {
    __shared__ __align__(16) u16 s_tile[64][72];      // Q staging only
    __shared__ __align__(16) u16 s_p[4][16][136];     // per-wave P chunk (A-layout)
    __shared__ unsigned long long m_bits[8];

    int id = blockIdx.x;
    int t_ = id >> 3;
    int mtile = t_ & 7;
    int bh = (id & 7) + ((t_ >> 3) << 3);
    int b = bh >> 4, h = bh & 15;
    int tid = threadIdx.x, lane = tid & 63, wave = tid >> 6;
    int lrow = lane & 15, quad = lane >> 4;
    int m0 = mtile * 64;

    const u16* Qbase = qkv + (long)(b * 512) * 3072 + h * 64;
    const u16* Kbase = Qbase + 1024;

    {   // mask bitmask: bit j of m_bits[c] = (mask[b*512 + c*64 + j] != 0)
        int i0 = wave * 64 + lane;
        unsigned long long bl0 = __ballot(mask[b * 512 + i0] != 0);
        if (lane == 0) m_bits[wave] = bl0;
        unsigned long long bl1 = __ballot(mask[b * 512 + 256 + i0] != 0);
        if (lane == 0) m_bits[4 + wave] = bl1;
    }

    // stage Q tile [64][64]
#pragma unroll
    for (int i = 0; i < 2; i++) {
        int idx = i * 256 + tid;
        int r = idx >> 3, c = (idx & 7) * 8;
        *(uint4*)&s_tile[r][c] = *(const uint4*)(Qbase + (long)(m0 + r) * 3072 + c);
    }
    __syncthreads();
    bf16x8 qf[2];
    qf[0] = *(const bf16x8*)&s_tile[wave * 16 + lrow][0 + quad * 8];
    qf[1] = *(const bf16x8*)&s_tile[wave * 16 + lrow][32 + quad * 8];

    f32x4 sacc[32];
#pragma unroll
    for (int t = 0; t < 32; t++) sacc[t] = (f32x4){0.f, 0.f, 0.f, 0.f};

    // S = Q K^T, K fragments direct from global (L2-hit)
#pragma unroll
    for (int t = 0; t < 32; t++) {
        const u16* krow = Kbase + (long)(t * 16 + lrow) * 3072 + quad * 8;
        bf16x8 b0 = *(const bf16x8*)krow;
        bf16x8 b1 = *(const bf16x8*)(krow + 32);
        sacc[t] = __builtin_amdgcn_mfma_f32_16x16x32_bf16(qf[0], b0, sacc[t], 0, 0, 0);
        sacc[t] = __builtin_amdgcn_mfma_f32_16x16x32_bf16(qf[1], b1, sacc[t], 0, 0, 0);
    }

    // mask + scale; lane holds rows quad*4+r, cols t*16+lrow
    float mx[4] = {-3.0e38f, -3.0e38f, -3.0e38f, -3.0e38f};
#pragma unroll
    for (int t = 0; t < 32; t++) {
        int col = t * 16 + lrow;
        int on = (int)((m_bits[col >> 6] >> (col & 63)) & 1ull);
#pragma unroll
        for (int r = 0; r < 4; r++) {
            float s = on ? sacc[t][r] * 0.125f : -1e9f;
            sacc[t][r] = s;
            mx[r] = fmaxf(mx[r], s);
        }
    }
#pragma unroll
    for (int off = 1; off < 16; off <<= 1)
#pragma unroll
        for (int r = 0; r < 4; r++) mx[r] = fmaxf(mx[r], __shfl_xor(mx[r], off));
    float sm[4] = {0.f, 0.f, 0.f, 0.f};
#pragma unroll
    for (int t = 0; t < 32; t++)
#pragma unroll
        for (int r = 0; r < 4; r++) {
            float e = __expf(sacc[t][r] - mx[r]);
            sacc[t][r] = e;
            sm[r] += e;
        }
#pragma unroll
    for (int off = 1; off < 16; off <<= 1)
#pragma unroll
        for (int r = 0; r < 4; r++) sm[r] += __shfl_xor(sm[r], off);
#pragma unroll
    for (int r = 0; r < 4; r++) sm[r] = 1.0f / sm[r];
#pragma unroll
    for (int t = 0; t < 32; t++)
#pragma unroll
        for (int r = 0; r < 4; r++) sacc[t][r] *= sm[r];

    // PV + prob write-out, per 128-key chunk; s_p is wave-private (no barriers)
    f32x4 cacc[4];
#pragma unroll
    for (int ni = 0; ni < 4; ni++) cacc[ni] = (f32x4){0.f, 0.f, 0.f, 0.f};
    const u16* vh = vT + (long)bh * 64 * 512;
    int prr = lane >> 5;       // row parity for prob write
    int pcc = lane & 31;       // float4 index within 128-col chunk

    for (int nc = 0; nc < 4; nc++) {
#pragma unroll
        for (int t2 = 0; t2 < 8; t2++) {
            int t = nc * 8 + t2;
#pragma unroll
            for (int r = 0; r < 4; r++)
                s_p[wave][quad * 4 + r][t2 * 16 + lrow] = f2b(sacc[t][r]);
        }

        // coalesced probs write-out of this wave's 16x128 chunk
        {
            float* abase = attnOut + (long)bh * 512 * 512
                         + (long)(m0 + wave * 16) * 512 + nc * 128;
#pragma unroll
            for (int i = 0; i < 8; i++) {
                int row = i * 2 + prr;
                uint2 pv = *(const uint2*)&s_p[wave][row][pcc * 4];
                float4 o;
                o.x = b2f_u32(pv.x << 16);
                o.y = b2f_u32(pv.x & 0xffff0000u);
                o.z = b2f_u32(pv.y << 16);
                o.w = b2f_u32(pv.y & 0xffff0000u);
                *(float4*)(abase + (long)row * 512 + pcc * 4) = o;
            }
        }

#pragma unroll
        for (int kk = 0; kk < 4; kk++) {
            bf16x8 pf = *(const bf16x8*)&s_p[wave][lrow][kk * 32 + quad * 8];
#pragma unroll
            for (int ni = 0; ni < 4; ni++) {
                bf16x8 vf = *(const bf16x8*)(vh + (long)(ni * 16 + lrow) * 512 + nc * 128 + kk * 32 + quad * 8);
                cacc[ni] = __builtin_amdgcn_mfma_f32_16x16x32_bf16(pf, vf, cacc[ni], 0, 0, 0);
            }
        }
    }

    u16* crow = ctx + (long)(b * 512 + m0 + wave * 16 + quad * 4) * 1024 + h * 64 + lrow;
#pragma unroll
    for (int ni = 0; ni < 4; ni++)
#pragma unroll
        for (int r = 0; r < 4; r++) crow[(long)r * 1024 + ni * 16] = f2b(cacc[ni][r]);
}

// ---------------- out = LayerNorm(a + r) * g + beta ----------------
__global__ __launch_bounds__(256) void add_ln(const u16* __restrict__ a,
                                              const void* __restrict__ r, int r_fp32,
                                              const float* __restrict__ g,
                                              const float* __restrict__ beta,
                                              void* __restrict__ out, int out_fp32) {
    long row = blockIdx.x;
    const u16* pa = a + row * 1024;
    int tid = threadIdx.x;
    float v[4];
    float sum = 0.f, sq = 0.f;
#pragma unroll
    for (int j = 0; j < 4; j++) {
        int c = tid + j * 256;
        float rv = r_fp32 ? ((const float*)r)[row * 1024 + c]
                          : b2f(((const u16*)r)[row * 1024 + c]);
        float x = b2f(pa[c]) + rv;
        v[j] = x;
        sum += x;
        sq += x * x;
    }
#pragma unroll
    for (int off = 32; off >= 1; off >>= 1) {
        sum += __shfl_xor(sum, off);
        sq += __shfl_xor(sq, off);
    }
    __shared__ float red[2][4];
    int wave = tid >> 6, lane = tid & 63;
    if (lane == 0) { red[0][wave] = sum; red[1][wave] = sq; }
    __syncthreads();
    sum = red[0][0] + red[0][1] + red[0][2] + red[0][3];
    sq = red[1][0] + red[1][1] + red[1][2] + red[1][3];
    float mu = sum * (1.f / 1024.f);
    float var = sq * (1.f / 1024.f) - mu * mu;
    float rstd = rsqrtf(var + 1e-6f);
#pragma unroll
    for (int j = 0; j < 4; j++) {
        int c = tid + j * 256;
        float y = (v[j] - mu) * rstd * g[c] + beta[c];
        if (out_fp32) ((float*)out)[row * 1024 + c] = y;
        else ((u16*)out)[row * 1024 + c] = f2b(y);
    }
}

extern "C" void kernel_launch(void* const* d_in, const int* in_sizes, int n_in,
                              void* d_out, int out_size, void* d_ws, size_t ws_size,
                              hipStream_t stream) {
    const float* x   = (const float*)d_in[0];
    const float* Wq  = (const float*)d_in[1];
    const float* bq  = (const float*)d_in[2];
    const float* Wk  = (const float*)d_in[3];
    const float* bk  = (const float*)d_in[4];
    const float* Wv  = (const float*)d_in[5];
    const float* bv  = (const float*)d_in[6];
    const float* Wo  = (const float*)d_in[7];
    const float* bo  = (const float*)d_in[8];
    const float* g1  = (const float*)d_in[9];
    const float* be1 = (const float*)d_in[10];
    const float* w1  = (const float*)d_in[11];
    const float* b1  = (const float*)d_in[12];
    const float* w2  = (const float*)d_in[13];
    const float* b2  = (const float*)d_in[14];
    const float* g2  = (const float*)d_in[15];
    const float* be2 = (const float*)d_in[16];
    const int* mask  = (const int*)d_in[17];

    float* out = (float*)d_out;                   // [8192][1024] fp32
    float* attn = out + (long)8192 * 1024;        // [256][512][512] fp32

    char* w = (char*)d_ws;
    auto alloc = [&](size_t bytes) {
        char* p = w;
        w += (bytes + 255) & ~(size_t)255;
        return p;
    };
    u16* WqkvT = (u16*)alloc(3072L * 1024 * 2);
    u16* WoT   = (u16*)alloc(1024L * 1024 * 2);
    u16* w1T   = (u16*)alloc(4096L * 1024 * 2);
    u16* w2T   = (u16*)alloc(1024L * 4096 * 2);
    float* bqkv = (float*)alloc(3072L * 4);
    u16* xb    = (u16*)alloc(8192L * 1024 * 2);
    char* P1 = alloc(8192L * 4096 * 2);  // qkv (48MB) -> ff (64MB)
    u16* qkv = (u16*)P1;
    u16* ff  = (u16*)P1;
    char* P2 = alloc(256L * 64 * 512 * 2);  // vT -> y2
    u16* vT = (u16*)P2;
    u16* y2 = (u16*)P2;
    u16* ctx = (u16*)alloc(8192L * 1024 * 2);
    u16* x1  = (u16*)alloc(8192L * 1024 * 2);
    u16* y   = (u16*)alloc(8192L * 1024 * 2);

    dim3 blk(256);

    transpose_f2b<<<dim3(32, 32), blk, 0, stream>>>(Wq, WqkvT, 1024, 1024);
    transpose_f2b<<<dim3(32, 32), blk, 0, stream>>>(Wk, WqkvT + 1024L * 1024, 1024, 1024);
    transpose_f2b<<<dim3(32, 32), blk, 0, stream>>>(Wv, WqkvT + 2048L * 1024, 1024, 1024);
    transpose_f2b<<<dim3(32, 32), blk, 0, stream>>>(Wo, WoT, 1024, 1024);
    transpose_f2b<<<dim3(128, 32), blk, 0, stream>>>(w1, w1T, 1024, 4096);
    transpose_f2b<<<dim3(32, 128), blk, 0, stream>>>(w2, w2T, 4096, 1024);
    concat3<<<12, blk, 0, stream>>>(bq, bk, bv, bqkv);
    conv_f2b<<<8192, blk, 0, stream>>>(x, xb, 8192L * 1024);

    // qkv = xb @ [Wq|Wk|Wv]^T + bqkv   (M=8192, N=3072, K=1024) — 256^2 8-phase
    gemm_bt256<<<dim3(384), dim3(512), 0, stream>>>(
        xb, WqkvT, bqkv, qkv, 8192, 3072, 1024, 1024, 1024, 3072, 0, 12);

    split_v<<<dim3(16, 2, 256), blk, 0, stream>>>(qkv, vT);

    // fused attention: probs -> attn (fp32), ctx (bf16 merged heads)
    attn_fused<<<dim3(2048), blk, 0, stream>>>(qkv, vT, mask, attn, ctx);

    // y = ctx @ Wo^T + bo   (M=8192, N=1024, K=1024) — 128x256 2-phase, 256 blocks
    gemm_btn<<<dim3(256), dim3(512), 0, stream>>>(
        ctx, WoT, bo, y, 1024, 1024, 1024, 1024, 0, 4);

    // x1 = LN(y + x)
    add_ln<<<8192, blk, 0, stream>>>(y, x, 1, g1, be1, x1, 0);

    // ff = relu(x1 @ w1^T + b1)   (M=8192, N=4096, K=1024) — 256^2 8-phase
    gemm_bt256<<<dim3(512), dim3(512), 0, stream>>>(
        x1, w1T, b1, ff, 8192, 4096, 1024, 1024, 1024, 4096, 1, 16);

    // y2 = ff @ w2^T + b2   (M=8192, N=1024, K=4096) — 128x256 2-phase, 256 blocks
    gemm_btn<<<dim3(256), dim3(512), 0, stream>>>(
        ff, w2T, b2, y2, 4096, 4096, 4096, 1024, 0, 4);

    // out = LN(y2 + x1)
    add_ln<<<8192, blk, 0, stream>>>(y2, x1, 0, g2, be2, out, 1);
}

// Round 4
// 829.155 us; speedup vs baseline: 1.0493x; 1.0493x over previous
//
#include <hip/hip_runtime.h>
#include <hip/hip_bf16.h>

typedef unsigned short u16;
typedef __bf16 bf16x8 __attribute__((ext_vector_type(8)));
typedef float f32x4 __attribute__((ext_vector_type(4)));

static __device__ __forceinline__ float b2f(u16 x) {
    unsigned int u = ((unsigned int)x) << 16;
    float f; __builtin_memcpy(&f, &u, 4); return f;
}
static __device__ __forceinline__ float b2f_u32(unsigned int u) {
    float f; __builtin_memcpy(&f, &u, 4); return f;
}
static __device__ __forceinline__ u16 f2b(float f) {
    unsigned int u; __builtin_memcpy(&u, &f, 4);
    unsigned int lsb = (u >> 16) & 1u;
    u += 0x7fffu + lsb;
    return (u16)(u >> 16);
}

// async 16B global->LDS (wave-uniform LDS base + lane*16)
static __device__ __forceinline__ void gload16(const u16* g, u16* l) {
    __builtin_amdgcn_global_load_lds(
        (const __attribute__((address_space(1))) unsigned int*)g,
        (__attribute__((address_space(3))) unsigned int*)l, 16, 0, 0);
}

// ---------------- transpose+convert: src fp32 [R][C] -> dst bf16 [C][R] ----------------
__global__ __launch_bounds__(256) void transpose_f2b(const float* __restrict__ src,
                                                     u16* __restrict__ dst,
                                                     int R, int C) {
    __shared__ u16 tile[32][33];
    int c0 = blockIdx.x * 32, r0 = blockIdx.y * 32;
    int tx = threadIdx.x & 31, ty = threadIdx.x >> 5;
    for (int i = ty; i < 32; i += 8) {
        int r = r0 + i, c = c0 + tx;
        tile[i][tx] = (r < R && c < C) ? f2b(src[(long)r * C + c]) : (u16)0;
    }
    __syncthreads();
    for (int i = ty; i < 32; i += 8) {
        int c = c0 + i, r = r0 + tx;
        if (c < C && r < R) dst[(long)c * R + r] = tile[tx][i];
    }
}

// ---------------- concat 3 fp32 bias vectors of 1024 ----------------
__global__ __launch_bounds__(256) void concat3(const float* a, const float* b, const float* c,
                                               float* out) {
    int i = blockIdx.x * 256 + threadIdx.x;
    if (i < 1024) out[i] = a[i];
    else if (i < 2048) out[i] = b[i - 1024];
    else if (i < 3072) out[i] = c[i - 2048];
}

// ---------------- fp32 -> bf16 bulk convert ----------------
__global__ __launch_bounds__(256) void conv_f2b(const float* __restrict__ src,
                                                u16* __restrict__ dst, long n) {
    long i = ((long)blockIdx.x * 256 + threadIdx.x) * 4;
    if (i >= n) return;
    float4 f = *(const float4*)(src + i);
    ushort4 o;
    o.x = f2b(f.x); o.y = f2b(f.y); o.z = f2b(f.z); o.w = f2b(f.w);
    *(ushort4*)(dst + i) = o;
}

// ---------------- 256x256 8-phase bt-GEMM (T2 swizzle + T3/T4 counted vmcnt + T5) ----
__global__ __launch_bounds__(512, 1) void gemm_bt256(
    const u16* __restrict__ A, const u16* __restrict__ B,
    const float* __restrict__ bias, u16* __restrict__ C,
    int M, int N, int K, int lda, int ldb, int ldc, int relu, int nbx) {
    __shared__ __align__(16) u16 lds[2][4][8192];

    int nwg = gridDim.x;
    int id = blockIdx.x;
    int swz = (id & 7) * (nwg >> 3) + (id >> 3);   // nwg % 8 == 0 at all call sites
    int bx = swz % nbx, by = swz / nbx;
    long m0 = (long)by * 256, n0 = (long)bx * 256;

    int tid = threadIdx.x, lane = tid & 63, wave = tid >> 6;
    int lrow = lane & 15, quad = lane >> 4;
    int wm2 = wave >> 2;        // M-half of wave (interleaved 16-row slabs)
    int wn2 = wave & 3;         // N-group of wave (interleaved 16-col slabs)

    int laneRd = (lrow * 64 + quad * 16) ^ (((lrow >> 3) & 1) << 5);
    int Sl = (lane * 16) ^ (((lane >> 5) & 1) << 5);
    int wr = (Sl >> 6) & 15;
    int wb = Sl & 63;

    f32x4 acc[8][4];
#pragma unroll
    for (int i = 0; i < 8; i++)
#pragma unroll
        for (int j = 0; j < 4; j++) acc[i][j] = (f32x4){0.f, 0.f, 0.f, 0.f};
    bf16x8 af[4][2], bfr[2][2];

#define STAGE_HT(nb, ht, kt) do {                                              \
    const char* _gb = ((ht) < 2)                                               \
        ? (const char*)(A + (m0 + (ht) * 128) * lda)                           \
        : (const char*)(B + (n0 + ((ht) - 2) * 128) * ldb);                    \
    long _ld = (long)(((ht) < 2) ? lda : ldb) * 2;                             \
    _Pragma("unroll")                                                          \
    for (int j = 0; j < 2; j++) {                                              \
        int sub = j * 8 + wave;                                                \
        int srow = (sub >> 1) * 16 + wr;                                       \
        int scolb = (sub & 1) * 64 + wb;                                       \
        gload16((const u16*)(_gb + (long)srow * _ld + (long)(kt) * 128 + scolb),\
                &lds[nb][ht][sub << 9]);                                       \
    }                                                                          \
} while (0)

#define DSLOAD_A(qm) do {                                                      \
    const char* _p = _ab + ((qm) << 14);                                       \
    _Pragma("unroll") for (int mi = 0; mi < 4; mi++)                           \
    _Pragma("unroll") for (int kk = 0; kk < 2; kk++)                           \
        af[mi][kk] = *(const bf16x8*)(_p + ((mi * 4 + kk) << 10));             \
} while (0)

#define DSLOAD_B(qn) do {                                                      \
    const char* _p = _bb + ((qn) << 14);                                       \
    _Pragma("unroll") for (int ni = 0; ni < 2; ni++)                           \
    _Pragma("unroll") for (int kk = 0; kk < 2; kk++)                           \
        bfr[ni][kk] = *(const bf16x8*)(_p + ((ni * 8 + kk) << 10));            \
} while (0)

#define DOMFMA(qm, qn) do {                                                    \
    __builtin_amdgcn_s_setprio(1);                                             \
    _Pragma("unroll") for (int mi = 0; mi < 4; mi++)                           \
    _Pragma("unroll") for (int ni = 0; ni < 2; ni++)                           \
    _Pragma("unroll") for (int kk = 0; kk < 2; kk++)                           \
        acc[(qm) * 4 + mi][(qn) * 2 + ni] =                                    \
            __builtin_amdgcn_mfma_f32_16x16x32_bf16(                           \
                af[mi][kk], bfr[ni][kk], acc[(qm) * 4 + mi][(qn) * 2 + ni],    \
                0, 0, 0);                                                      \
    __builtin_amdgcn_s_setprio(0);                                             \
} while (0)

#define MIDBAR()  do { __builtin_amdgcn_s_barrier(); __builtin_amdgcn_sched_barrier(0); } while (0)
#define ENDBAR()  do { __builtin_amdgcn_sched_barrier(0); __builtin_amdgcn_s_barrier(); } while (0)

    int NT = K >> 6;
    STAGE_HT(0, 0, 0);
    STAGE_HT(0, 2, 0);
    STAGE_HT(0, 1, 0);
    STAGE_HT(0, 3, 0);

    for (int t = 0; t < NT - 1; t++) {
        int cur = t & 1, nxt = cur ^ 1;
        const char* _ab = (const char*)&lds[cur][0][0] + (wm2 << 11) + laneRd;
        const char* _bb = (const char*)&lds[cur][2][0] + (wn2 << 11) + laneRd;
        STAGE_HT(nxt, 0, t + 1);
        asm volatile("s_waitcnt vmcnt(6)" ::: "memory");
        MIDBAR();
        DSLOAD_A(0); DSLOAD_B(0); DOMFMA(0, 0);
        ENDBAR();
        STAGE_HT(nxt, 2, t + 1);
        asm volatile("s_waitcnt vmcnt(6)" ::: "memory");
        MIDBAR();
        DSLOAD_A(1); DOMFMA(1, 0);
        ENDBAR();
        STAGE_HT(nxt, 1, t + 1);
        asm volatile("s_waitcnt vmcnt(6)" ::: "memory");
        MIDBAR();
        DSLOAD_B(1); DOMFMA(1, 1);
        ENDBAR();
        STAGE_HT(nxt, 3, t + 1);
        MIDBAR();
        DSLOAD_A(0); DOMFMA(0, 1);
        ENDBAR();
    }
    {   // tail tile: drain 4 -> 2 -> 0
        int cur = (NT - 1) & 1;
        const char* _ab = (const char*)&lds[cur][0][0] + (wm2 << 11) + laneRd;
        const char* _bb = (const char*)&lds[cur][2][0] + (wn2 << 11) + laneRd;
        asm volatile("s_waitcnt vmcnt(4)" ::: "memory");
        MIDBAR();
        DSLOAD_A(0); DSLOAD_B(0); DOMFMA(0, 0);
        ENDBAR();
        asm volatile("s_waitcnt vmcnt(2)" ::: "memory");
        MIDBAR();
        DSLOAD_A(1); DOMFMA(1, 0);
        ENDBAR();
        asm volatile("s_waitcnt vmcnt(0)" ::: "memory");
        MIDBAR();
        DSLOAD_B(1); DOMFMA(1, 1);
        ENDBAR();
        DSLOAD_A(0); DOMFMA(0, 1);
    }

#pragma unroll
    for (int mg = 0; mg < 8; mg++) {
        long row0 = m0 + (long)(((mg >> 2) * 8 + (mg & 3) * 2 + wm2) * 16 + quad * 4);
#pragma unroll
        for (int ng = 0; ng < 4; ng++) {
            long col = n0 + ((ng >> 1) * 8 + (ng & 1) * 4 + wn2) * 16 + lrow;
            float bv = bias ? bias[col] : 0.f;
#pragma unroll
            for (int r = 0; r < 4; r++) {
                float v = acc[mg][ng][r] + bv;
                if (relu) v = fmaxf(v, 0.f);
                C[(row0 + r) * ldc + col] = f2b(v);
            }
        }
    }
#undef STAGE_HT
#undef DSLOAD_A
#undef DSLOAD_B
#undef DOMFMA
}

// ---------------- 128x256 2-phase counted-vmcnt bt-GEMM (for N=1024 shapes) --------
__global__ __launch_bounds__(512, 1) void gemm_btn(
    const u16* __restrict__ A, const u16* __restrict__ B,
    const float* __restrict__ bias, u16* __restrict__ C,
    int K, int lda, int ldb, int ldc, int relu, int nbx) {
    __shared__ __align__(16) u16 lds[2][3][8192];

    int nwg = gridDim.x;
    int id = blockIdx.x;
    int swz = (id & 7) * (nwg >> 3) + (id >> 3);
    int bx = swz % nbx, by = swz / nbx;
    long m0 = (long)by * 128, n0 = (long)bx * 256;

    int tid = threadIdx.x, lane = tid & 63, wave = tid >> 6;
    int lrow = lane & 15, quad = lane >> 4;
    int wm2 = wave >> 2;
    int wn2 = wave & 3;

    int laneRd = (lrow * 64 + quad * 16) ^ (((lrow >> 3) & 1) << 5);
    int Sl = (lane * 16) ^ (((lane >> 5) & 1) << 5);
    int wr = (Sl >> 6) & 15;
    int wb = Sl & 63;

    f32x4 acc[4][4];
#pragma unroll
    for (int i = 0; i < 4; i++)
#pragma unroll
        for (int j = 0; j < 4; j++) acc[i][j] = (f32x4){0.f, 0.f, 0.f, 0.f};
    bf16x8 af[4][2], bfr[2][2];

#define STAGE_HT(nb, ht, kt) do {                                              \
    const char* _gb = ((ht) == 0)                                              \
        ? (const char*)(A + m0 * lda)                                          \
        : (const char*)(B + (n0 + ((ht) - 1) * 128) * ldb);                    \
    long _ld = (long)(((ht) == 0) ? lda : ldb) * 2;                            \
    _Pragma("unroll")                                                          \
    for (int j = 0; j < 2; j++) {                                              \
        int sub = j * 8 + wave;                                                \
        int srow = (sub >> 1) * 16 + wr;                                       \
        int scolb = (sub & 1) * 64 + wb;                                       \
        gload16((const u16*)(_gb + (long)srow * _ld + (long)(kt) * 128 + scolb),\
                &lds[nb][ht][sub << 9]);                                       \
    }                                                                          \
} while (0)

#define DSLOAD_A() do {                                                        \
    _Pragma("unroll") for (int mi = 0; mi < 4; mi++)                           \
    _Pragma("unroll") for (int kk = 0; kk < 2; kk++)                           \
        af[mi][kk] = *(const bf16x8*)(_ab + ((mi * 4 + kk) << 10));            \
} while (0)

#define DSLOAD_B(qn) do {                                                      \
    const char* _p = _b0 + (qn) * 16384;                                       \
    _Pragma("unroll") for (int ni = 0; ni < 2; ni++)                           \
    _Pragma("unroll") for (int kk = 0; kk < 2; kk++)                           \
        bfr[ni][kk] = *(const bf16x8*)(_p + ((ni * 8 + kk) << 10));            \
} while (0)

#define DOMFMA(qn) do {                                                        \
    __builtin_amdgcn_s_setprio(1);                                             \
    _Pragma("unroll") for (int mi = 0; mi < 4; mi++)                           \
    _Pragma("unroll") for (int ni = 0; ni < 2; ni++)                           \
    _Pragma("unroll") for (int kk = 0; kk < 2; kk++)                           \
        acc[mi][(qn) * 2 + ni] =                                               \
            __builtin_amdgcn_mfma_f32_16x16x32_bf16(                           \
                af[mi][kk], bfr[ni][kk], acc[mi][(qn) * 2 + ni], 0, 0, 0);     \
    __builtin_amdgcn_s_setprio(0);                                             \
} while (0)

    int NT = K >> 6;
    STAGE_HT(0, 0, 0);
    STAGE_HT(0, 1, 0);
    STAGE_HT(0, 2, 0);

    for (int t = 0; t < NT - 1; t++) {
        int cur = t & 1, nxt = cur ^ 1;
        const char* _ab = (const char*)&lds[cur][0][0] + (wm2 << 11) + laneRd;
        const char* _b0 = (const char*)&lds[cur][1][0] + (wn2 << 11) + laneRd;
        STAGE_HT(nxt, 0, t + 1);
        asm volatile("s_waitcnt vmcnt(4)" ::: "memory");
        MIDBAR();
        DSLOAD_A(); DSLOAD_B(0); DOMFMA(0);
        ENDBAR();
        STAGE_HT(nxt, 1, t + 1);
        STAGE_HT(nxt, 2, t + 1);
        asm volatile("s_waitcnt vmcnt(6)" ::: "memory");
        MIDBAR();
        DSLOAD_B(1); DOMFMA(1);
        ENDBAR();
    }
    {   // tail tile: drain 2 -> 0
        int cur = (NT - 1) & 1;
        const char* _ab = (const char*)&lds[cur][0][0] + (wm2 << 11) + laneRd;
        const char* _b0 = (const char*)&lds[cur][1][0] + (wn2 << 11) + laneRd;
        asm volatile("s_waitcnt vmcnt(2)" ::: "memory");
        MIDBAR();
        DSLOAD_A(); DSLOAD_B(0); DOMFMA(0);
        ENDBAR();
        asm volatile("s_waitcnt vmcnt(0)" ::: "memory");
        MIDBAR();
        DSLOAD_B(1); DOMFMA(1);
    }

#pragma unroll
    for (int mi = 0; mi < 4; mi++) {
        long row0 = m0 + (long)((mi * 2 + wm2) * 16 + quad * 4);
#pragma unroll
        for (int ng = 0; ng < 4; ng++) {
            long col = n0 + ((ng >> 1) * 8 + (ng & 1) * 4 + wn2) * 16 + lrow;
            float bv = bias ? bias[col] : 0.f;
#pragma unroll
            for (int r = 0; r < 4; r++) {
                float v = acc[mi][ng][r] + bv;
                if (relu) v = fmaxf(v, 0.f);
                C[(row0 + r) * ldc + col] = f2b(v);
            }
        }
    }
#undef STAGE_HT
#undef DSLOAD_A
#undef DSLOAD_B
#undef DOMFMA
#undef MIDBAR
#undef ENDBAR
}

// ---------------- extract v from qkv (bf16), transposed per head ----------------
__global__ __launch_bounds__(256) void split_v(const u16* __restrict__ qkv,
                                               u16* __restrict__ vT) {
    __shared__ u16 tile[32][33];
    int bh = blockIdx.z;
    int b = bh >> 4, h = bh & 15;
    int s0 = blockIdx.x * 32;
    int d0 = blockIdx.y * 32;
    int tx = threadIdx.x & 31, ty = threadIdx.x >> 5;
    for (int i = ty; i < 32; i += 8)
        tile[i][tx] = qkv[((long)(b * 512 + s0 + i)) * 3072 + 2048 + h * 64 + d0 + tx];
    __syncthreads();
    for (int i = ty; i < 32; i += 8)
        vT[((long)bh * 64 + d0 + i) * 512 + s0 + tx] = tile[tx][i];
}

// ---------------- fused attention: scores + mask + softmax + PV ----------------
// Staged-K (coalesced uint4 -> LDS; direct-global K fragments proven 24% slower
// in round 2: 64-line scatter per instruction). T14 async-stage: K chunk nc+1
// prefetched into registers under chunk nc's MFMA. s_p is wave-private ->
// barrier-free PV (proven in round 2).
__global__ __launch_bounds__(256) void attn_fused(
    const u16* __restrict__ qkv, const u16* __restrict__ vT,
    const int* __restrict__ mask, float* __restrict__ attnOut,
    u16* __restrict__ ctx) {
    __shared__ __align__(16) u16 s_tile[128][72];     // Q then K-chunk staging
    __shared__ __align__(16) u16 s_p[4][16][136];     // per-wave P chunk (A-layout)
    __shared__ unsigned long long m_bits[8];

    // XCD-aware decode: xcd = id&7 owns bh === xcd (mod 8)
    int id = blockIdx.x;
    int t_ = id >> 3;
    int mtile = t_ & 7;
    int bh = (id & 7) + ((t_ >> 3) << 3);
    int b = bh >> 4, h = bh & 15;
    int tid = threadIdx.x, lane = tid & 63, wave = tid >> 6;
    int lrow = lane & 15, quad = lane >> 4;
    int m0 = mtile * 64;

    const u16* Qbase = qkv + (long)(b * 512) * 3072 + h * 64;
    const u16* Kbase = Qbase + 1024;

    {   // mask bitmask: bit j of m_bits[c] = (mask[b*512 + c*64 + j] != 0)
        int i0 = wave * 64 + lane;
        unsigned long long bl0 = __ballot(mask[b * 512 + i0] != 0);
        if (lane == 0) m_bits[wave] = bl0;
        unsigned long long bl1 = __ballot(mask[b * 512 + 256 + i0] != 0);
        if (lane == 0) m_bits[4 + wave] = bl1;
    }

    // stage Q tile [64][64]
#pragma unroll
    for (int i = 0; i < 2; i++) {
        int idx = i * 256 + tid;
        int r = idx >> 3, c = (idx & 7) * 8;
        *(uint4*)&s_tile[r][c] = *(const uint4*)(Qbase + (long)(m0 + r) * 3072 + c);
    }
    // T14 prefetch: K chunk 0 into registers (overlaps Q staging / barrier)
    uint4 kreg[4];
#pragma unroll
    for (int i = 0; i < 4; i++) {
        int idx = i * 256 + tid;
        int r = idx >> 3, c = (idx & 7) * 8;
        kreg[i] = *(const uint4*)(Kbase + (long)r * 3072 + c);
    }
    __syncthreads();
    bf16x8 qf[2];
    qf[0] = *(const bf16x8*)&s_tile[wave * 16 + lrow][0 + quad * 8];
    qf[1] = *(const bf16x8*)&s_tile[wave * 16 + lrow][32 + quad * 8];
    __syncthreads();   // all waves have Q fragments before K overwrites s_tile

    f32x4 sacc[32];
#pragma unroll
    for (int t = 0; t < 32; t++) sacc[t] = (f32x4){0.f, 0.f, 0.f, 0.f};

    // S = Q K^T over 4 chunks of 128 key-rows; prefetch nc+1 under nc's MFMA
    for (int nc = 0; nc < 4; nc++) {
#pragma unroll
        for (int i = 0; i < 4; i++) {
            int idx = i * 256 + tid;
            int r = idx >> 3, c = (idx & 7) * 8;
            *(uint4*)&s_tile[r][c] = kreg[i];
        }
        __syncthreads();
        if (nc < 3) {
#pragma unroll
            for (int i = 0; i < 4; i++) {
                int idx = i * 256 + tid;
                int r = idx >> 3, c = (idx & 7) * 8;
                kreg[i] = *(const uint4*)(Kbase + (long)((nc + 1) * 128 + r) * 3072 + c);
            }
        }
#pragma unroll
        for (int ni = 0; ni < 8; ni++) {
            bf16x8 b0 = *(const bf16x8*)&s_tile[ni * 16 + lrow][0 + quad * 8];
            bf16x8 b1 = *(const bf16x8*)&s_tile[ni * 16 + lrow][32 + quad * 8];
            int t = nc * 8 + ni;
            sacc[t] = __builtin_amdgcn_mfma_f32_16x16x32_bf16(qf[0], b0, sacc[t], 0, 0, 0);
            sacc[t] = __builtin_amdgcn_mfma_f32_16x16x32_bf16(qf[1], b1, sacc[t], 0, 0, 0);
        }
        __syncthreads();
    }

    // mask + scale; lane holds rows quad*4+r, cols t*16+lrow
    float mx[4] = {-3.0e38f, -3.0e38f, -3.0e38f, -3.0e38f};
#pragma unroll
    for (int t = 0; t < 32; t++) {
        int col = t * 16 + lrow;
        int on = (int)((m_bits[col >> 6] >> (col & 63)) & 1ull);
#pragma unroll
        for (int r = 0; r < 4; r++) {
            float s = on ? sacc[t][r] * 0.125f : -1e9f;
            sacc[t][r] = s;
            mx[r] = fmaxf(mx[r], s);
        }
    }
#pragma unroll
    for (int off = 1; off < 16; off <<= 1)
#pragma unroll
        for (int r = 0; r < 4; r++) mx[r] = fmaxf(mx[r], __shfl_xor(mx[r], off));
    float sm[4] = {0.f, 0.f, 0.f, 0.f};
#pragma unroll
    for (int t = 0; t < 32; t++)
#pragma unroll
        for (int r = 0; r < 4; r++) {
            float e = __expf(sacc[t][r] - mx[r]);
            sacc[t][r] = e;
            sm[r] += e;
        }
#pragma unroll
    for (int off = 1; off < 16; off <<= 1)
#pragma unroll
        for (int r = 0; r < 4; r++) sm[r] += __shfl_xor(sm[r], off);
#pragma unroll
    for (int r = 0; r < 4; r++) sm[r] = 1.0f / sm[r];
#pragma unroll
    for (int t = 0; t < 32; t++)
#pragma unroll
        for (int r = 0; r < 4; r++) sacc[t][r] *= sm[r];

    // PV + prob write-out, per 128-key chunk; s_p wave-private (no barriers)
    f32x4 cacc[4];
#pragma unroll
    for (int ni = 0; ni < 4; ni++) cacc[ni] = (f32x4){0.f, 0.f, 0.f, 0.f};
    const u16* vh = vT + (long)bh * 64 * 512;
    int prr = lane >> 5;       // row parity for prob write
    int pcc = lane & 31;       // float4 index within 128-col chunk

    for (int nc = 0; nc < 4; nc++) {
#pragma unroll
        for (int t2 = 0; t2 < 8; t2++) {
            int t = nc * 8 + t2;
#pragma unroll
            for (int r = 0; r < 4; r++)
                s_p[wave][quad * 4 + r][t2 * 16 + lrow] = f2b(sacc[t][r]);
        }

        // coalesced probs write-out of this wave's 16x128 chunk
        {
            float* abase = attnOut + (long)bh * 512 * 512
                         + (long)(m0 + wave * 16) * 512 + nc * 128;
#pragma unroll
            for (int i = 0; i < 8; i++) {
                int row = i * 2 + prr;
                uint2 pv = *(const uint2*)&s_p[wave][row][pcc * 4];
                float4 o;
                o.x = b2f_u32(pv.x << 16);
                o.y = b2f_u32(pv.x & 0xffff0000u);
                o.z = b2f_u32(pv.y << 16);
                o.w = b2f_u32(pv.y & 0xffff0000u);
                *(float4*)(abase + (long)row * 512 + pcc * 4) = o;
            }
        }

#pragma unroll
        for (int kk = 0; kk < 4; kk++) {
            bf16x8 pf = *(const bf16x8*)&s_p[wave][lrow][kk * 32 + quad * 8];
#pragma unroll
            for (int ni = 0; ni < 4; ni++) {
                bf16x8 vf = *(const bf16x8*)(vh + (long)(ni * 16 + lrow) * 512 + nc * 128 + kk * 32 + quad * 8);
                cacc[ni] = __builtin_amdgcn_mfma_f32_16x16x32_bf16(pf, vf, cacc[ni], 0, 0, 0);
            }
        }
    }

    u16* crow = ctx + (long)(b * 512 + m0 + wave * 16 + quad * 4) * 1024 + h * 64 + lrow;
#pragma unroll
    for (int ni = 0; ni < 4; ni++)
#pragma unroll
        for (int r = 0; r < 4; r++) crow[(long)r * 1024 + ni * 16] = f2b(cacc[ni][r]);
}

// ---------------- out = LayerNorm(a + r) * g + beta ----------------
__global__ __launch_bounds__(256) void add_ln(const u16* __restrict__ a,
                                              const void* __restrict__ r, int r_fp32,
                                              const float* __restrict__ g,
                                              const float* __restrict__ beta,
                                              void* __restrict__ out, int out_fp32) {
    long row = blockIdx.x;
    const u16* pa = a + row * 1024;
    int tid = threadIdx.x;
    float v[4];
    float sum = 0.f, sq = 0.f;
#pragma unroll
    for (int j = 0; j < 4; j++) {
        int c = tid + j * 256;
        float rv = r_fp32 ? ((const float*)r)[row * 1024 + c]
                          : b2f(((const u16*)r)[row * 1024 + c]);
        float x = b2f(pa[c]) + rv;
        v[j] = x;
        sum += x;
        sq += x * x;
    }
#pragma unroll
    for (int off = 32; off >= 1; off >>= 1) {
        sum += __shfl_xor(sum, off);
        sq += __shfl_xor(sq, off);
    }
    __shared__ float red[2][4];
    int wave = tid >> 6, lane = tid & 63;
    if (lane == 0) { red[0][wave] = sum; red[1][wave] = sq; }
    __syncthreads();
    sum = red[0][0] + red[0][1] + red[0][2] + red[0][3];
    sq = red[1][0] + red[1][1] + red[1][2] + red[1][3];
    float mu = sum * (1.f / 1024.f);
    float var = sq * (1.f / 1024.f) - mu * mu;
    float rstd = rsqrtf(var + 1e-6f);
#pragma unroll
    for (int j = 0; j < 4; j++) {
        int c = tid + j * 256;
        float y = (v[j] - mu) * rstd * g[c] + beta[c];
        if (out_fp32) ((float*)out)[row * 1024 + c] = y;
        else ((u16*)out)[row * 1024 + c] = f2b(y);
    }
}

extern "C" void kernel_launch(void* const* d_in, const int* in_sizes, int n_in,
                              void* d_out, int out_size, void* d_ws, size_t ws_size,
                              hipStream_t stream) {
    const float* x   = (const float*)d_in[0];
    const float* Wq  = (const float*)d_in[1];
    const float* bq  = (const float*)d_in[2];
    const float* Wk  = (const float*)d_in[3];
    const float* bk  = (const float*)d_in[4];
    const float* Wv  = (const float*)d_in[5];
    const float* bv  = (const float*)d_in[6];
    const float* Wo  = (const float*)d_in[7];
    const float* bo  = (const float*)d_in[8];
    const float* g1  = (const float*)d_in[9];
    const float* be1 = (const float*)d_in[10];
    const float* w1  = (const float*)d_in[11];
    const float* b1  = (const float*)d_in[12];
    const float* w2  = (const float*)d_in[13];
    const float* b2  = (const float*)d_in[14];
    const float* g2  = (const float*)d_in[15];
    const float* be2 = (const float*)d_in[16];
    const int* mask  = (const int*)d_in[17];

    float* out = (float*)d_out;                   // [8192][1024] fp32
    float* attn = out + (long)8192 * 1024;        // [256][512][512] fp32

    char* w = (char*)d_ws;
    auto alloc = [&](size_t bytes) {
        char* p = w;
        w += (bytes + 255) & ~(size_t)255;
        return p;
    };
    u16* WqkvT = (u16*)alloc(3072L * 1024 * 2);
    u16* WoT   = (u16*)alloc(1024L * 1024 * 2);
    u16* w1T   = (u16*)alloc(4096L * 1024 * 2);
    u16* w2T   = (u16*)alloc(1024L * 4096 * 2);
    float* bqkv = (float*)alloc(3072L * 4);
    u16* xb    = (u16*)alloc(8192L * 1024 * 2);
    char* P1 = alloc(8192L * 4096 * 2);  // qkv (48MB) -> ff (64MB)
    u16* qkv = (u16*)P1;
    u16* ff  = (u16*)P1;
    char* P2 = alloc(256L * 64 * 512 * 2);  // vT -> y2
    u16* vT = (u16*)P2;
    u16* y2 = (u16*)P2;
    u16* ctx = (u16*)alloc(8192L * 1024 * 2);
    u16* x1  = (u16*)alloc(8192L * 1024 * 2);
    u16* y   = (u16*)alloc(8192L * 1024 * 2);

    dim3 blk(256);

    transpose_f2b<<<dim3(32, 32), blk, 0, stream>>>(Wq, WqkvT, 1024, 1024);
    transpose_f2b<<<dim3(32, 32), blk, 0, stream>>>(Wk, WqkvT + 1024L * 1024, 1024, 1024);
    transpose_f2b<<<dim3(32, 32), blk, 0, stream>>>(Wv, WqkvT + 2048L * 1024, 1024, 1024);
    transpose_f2b<<<dim3(32, 32), blk, 0, stream>>>(Wo, WoT, 1024, 1024);
    transpose_f2b<<<dim3(128, 32), blk, 0, stream>>>(w1, w1T, 1024, 4096);
    transpose_f2b<<<dim3(32, 128), blk, 0, stream>>>(w2, w2T, 4096, 1024);
    concat3<<<12, blk, 0, stream>>>(bq, bk, bv, bqkv);
    conv_f2b<<<8192, blk, 0, stream>>>(x, xb, 8192L * 1024);

    // qkv = xb @ [Wq|Wk|Wv]^T + bqkv   (M=8192, N=3072, K=1024) — 256^2 8-phase
    gemm_bt256<<<dim3(384), dim3(512), 0, stream>>>(
        xb, WqkvT, bqkv, qkv, 8192, 3072, 1024, 1024, 1024, 3072, 0, 12);

    split_v<<<dim3(16, 2, 256), blk, 0, stream>>>(qkv, vT);

    // fused attention: probs -> attn (fp32), ctx (bf16 merged heads)
    attn_fused<<<dim3(2048), blk, 0, stream>>>(qkv, vT, mask, attn, ctx);

    // y = ctx @ Wo^T + bo   (M=8192, N=1024, K=1024) — 128x256 2-phase, 256 blocks
    gemm_btn<<<dim3(256), dim3(512), 0, stream>>>(
        ctx, WoT, bo, y, 1024, 1024, 1024, 1024, 0, 4);

    // x1 = LN(y + x)
    add_ln<<<8192, blk, 0, stream>>>(y, x, 1, g1, be1, x1, 0);

    // ff = relu(x1 @ w1^T + b1)   (M=8192, N=4096, K=1024) — 256^2 8-phase
    gemm_bt256<<<dim3(512), dim3(512), 0, stream>>>(
        x1, w1T, b1, ff, 8192, 4096, 1024, 1024, 1024, 4096, 1, 16);

    // y2 = ff @ w2^T + b2   (M=8192, N=1024, K=4096) — 128x256 2-phase, 256 blocks
    gemm_btn<<<dim3(256), dim3(512), 0, stream>>>(
        ff, w2T, b2, y2, 4096, 4096, 4096, 1024, 0, 4);

    // out = LN(y2 + x1)
    add_ln<<<8192, blk, 0, stream>>>(y2, x1, 0, g2, be2, out, 1);
}

// Round 5
// 812.754 us; speedup vs baseline: 1.0705x; 1.0202x over previous
//
#include <hip/hip_runtime.h>
#include <hip/hip_bf16.h>

typedef unsigned short u16;
typedef __bf16 bf16x8 __attribute__((ext_vector_type(8)));
typedef float f32x4 __attribute__((ext_vector_type(4)));

static __device__ __forceinline__ float b2f(u16 x) {
    unsigned int u = ((unsigned int)x) << 16;
    float f; __builtin_memcpy(&f, &u, 4); return f;
}
static __device__ __forceinline__ float b2f_u32(unsigned int u) {
    float f; __builtin_memcpy(&f, &u, 4); return f;
}
static __device__ __forceinline__ u16 f2b(float f) {
    unsigned int u; __builtin_memcpy(&u, &f, 4);
    unsigned int lsb = (u >> 16) & 1u;
    u += 0x7fffu + lsb;
    return (u16)(u >> 16);
}

// async 16B global->LDS (wave-uniform LDS base + lane*16)
static __device__ __forceinline__ void gload16(const u16* g, u16* l) {
    __builtin_amdgcn_global_load_lds(
        (const __attribute__((address_space(1))) unsigned int*)g,
        (__attribute__((address_space(3))) unsigned int*)l, 16, 0, 0);
}

// ---------------- transpose+convert: src fp32 [R][C] -> dst bf16 [C][R] ----------------
__global__ __launch_bounds__(256) void transpose_f2b(const float* __restrict__ src,
                                                     u16* __restrict__ dst,
                                                     int R, int C) {
    __shared__ u16 tile[32][33];
    int c0 = blockIdx.x * 32, r0 = blockIdx.y * 32;
    int tx = threadIdx.x & 31, ty = threadIdx.x >> 5;
    for (int i = ty; i < 32; i += 8) {
        int r = r0 + i, c = c0 + tx;
        tile[i][tx] = (r < R && c < C) ? f2b(src[(long)r * C + c]) : (u16)0;
    }
    __syncthreads();
    for (int i = ty; i < 32; i += 8) {
        int c = c0 + i, r = r0 + tx;
        if (c < C && r < R) dst[(long)c * R + r] = tile[tx][i];
    }
}

// ---------------- concat 3 fp32 bias vectors of 1024 ----------------
__global__ __launch_bounds__(256) void concat3(const float* a, const float* b, const float* c,
                                               float* out) {
    int i = blockIdx.x * 256 + threadIdx.x;
    if (i < 1024) out[i] = a[i];
    else if (i < 2048) out[i] = b[i - 1024];
    else if (i < 3072) out[i] = c[i - 2048];
}

// ---------------- fp32 -> bf16 bulk convert ----------------
__global__ __launch_bounds__(256) void conv_f2b(const float* __restrict__ src,
                                                u16* __restrict__ dst, long n) {
    long i = ((long)blockIdx.x * 256 + threadIdx.x) * 4;
    if (i >= n) return;
    float4 f = *(const float4*)(src + i);
    ushort4 o;
    o.x = f2b(f.x); o.y = f2b(f.y); o.z = f2b(f.z); o.w = f2b(f.w);
    *(ushort4*)(dst + i) = o;
}

// ---------------- 256x256 8-phase bt-GEMM (T2 swizzle + T3/T4 counted vmcnt + T5) ----
__global__ __launch_bounds__(512, 1) void gemm_bt256(
    const u16* __restrict__ A, const u16* __restrict__ B,
    const float* __restrict__ bias, u16* __restrict__ C,
    int M, int N, int K, int lda, int ldb, int ldc, int relu, int nbx) {
    __shared__ __align__(16) u16 lds[2][4][8192];

    int nwg = gridDim.x;
    int id = blockIdx.x;
    int swz = (id & 7) * (nwg >> 3) + (id >> 3);   // nwg % 8 == 0 at all call sites
    int bx = swz % nbx, by = swz / nbx;
    long m0 = (long)by * 256, n0 = (long)bx * 256;

    int tid = threadIdx.x, lane = tid & 63, wave = tid >> 6;
    int lrow = lane & 15, quad = lane >> 4;
    int wm2 = wave >> 2;        // M-half of wave (interleaved 16-row slabs)
    int wn2 = wave & 3;         // N-group of wave (interleaved 16-col slabs)

    int laneRd = (lrow * 64 + quad * 16) ^ (((lrow >> 3) & 1) << 5);
    int Sl = (lane * 16) ^ (((lane >> 5) & 1) << 5);
    int wr = (Sl >> 6) & 15;
    int wb = Sl & 63;

    f32x4 acc[8][4];
#pragma unroll
    for (int i = 0; i < 8; i++)
#pragma unroll
        for (int j = 0; j < 4; j++) acc[i][j] = (f32x4){0.f, 0.f, 0.f, 0.f};
    bf16x8 af[4][2], bfr[2][2];

#define STAGE_HT(nb, ht, kt) do {                                              \
    const char* _gb = ((ht) < 2)                                               \
        ? (const char*)(A + (m0 + (ht) * 128) * lda)                           \
        : (const char*)(B + (n0 + ((ht) - 2) * 128) * ldb);                    \
    long _ld = (long)(((ht) < 2) ? lda : ldb) * 2;                             \
    _Pragma("unroll")                                                          \
    for (int j = 0; j < 2; j++) {                                              \
        int sub = j * 8 + wave;                                                \
        int srow = (sub >> 1) * 16 + wr;                                       \
        int scolb = (sub & 1) * 64 + wb;                                       \
        gload16((const u16*)(_gb + (long)srow * _ld + (long)(kt) * 128 + scolb),\
                &lds[nb][ht][sub << 9]);                                       \
    }                                                                          \
} while (0)

#define DSLOAD_A(qm) do {                                                      \
    const char* _p = _ab + ((qm) << 14);                                       \
    _Pragma("unroll") for (int mi = 0; mi < 4; mi++)                           \
    _Pragma("unroll") for (int kk = 0; kk < 2; kk++)                           \
        af[mi][kk] = *(const bf16x8*)(_p + ((mi * 4 + kk) << 10));             \
} while (0)

#define DSLOAD_B(qn) do {                                                      \
    const char* _p = _bb + ((qn) << 14);                                       \
    _Pragma("unroll") for (int ni = 0; ni < 2; ni++)                           \
    _Pragma("unroll") for (int kk = 0; kk < 2; kk++)                           \
        bfr[ni][kk] = *(const bf16x8*)(_p + ((ni * 8 + kk) << 10));            \
} while (0)

#define DOMFMA(qm, qn) do {                                                    \
    __builtin_amdgcn_s_setprio(1);                                             \
    _Pragma("unroll") for (int mi = 0; mi < 4; mi++)                           \
    _Pragma("unroll") for (int ni = 0; ni < 2; ni++)                           \
    _Pragma("unroll") for (int kk = 0; kk < 2; kk++)                           \
        acc[(qm) * 4 + mi][(qn) * 2 + ni] =                                    \
            __builtin_amdgcn_mfma_f32_16x16x32_bf16(                           \
                af[mi][kk], bfr[ni][kk], acc[(qm) * 4 + mi][(qn) * 2 + ni],    \
                0, 0, 0);                                                      \
    __builtin_amdgcn_s_setprio(0);                                             \
} while (0)

#define MIDBAR()  do { __builtin_amdgcn_s_barrier(); __builtin_amdgcn_sched_barrier(0); } while (0)
#define ENDBAR()  do { __builtin_amdgcn_sched_barrier(0); __builtin_amdgcn_s_barrier(); } while (0)

    int NT = K >> 6;
    STAGE_HT(0, 0, 0);
    STAGE_HT(0, 2, 0);
    STAGE_HT(0, 1, 0);
    STAGE_HT(0, 3, 0);

    for (int t = 0; t < NT - 1; t++) {
        int cur = t & 1, nxt = cur ^ 1;
        const char* _ab = (const char*)&lds[cur][0][0] + (wm2 << 11) + laneRd;
        const char* _bb = (const char*)&lds[cur][2][0] + (wn2 << 11) + laneRd;
        STAGE_HT(nxt, 0, t + 1);
        asm volatile("s_waitcnt vmcnt(6)" ::: "memory");
        MIDBAR();
        DSLOAD_A(0); DSLOAD_B(0); DOMFMA(0, 0);
        ENDBAR();
        STAGE_HT(nxt, 2, t + 1);
        asm volatile("s_waitcnt vmcnt(6)" ::: "memory");
        MIDBAR();
        DSLOAD_A(1); DOMFMA(1, 0);
        ENDBAR();
        STAGE_HT(nxt, 1, t + 1);
        asm volatile("s_waitcnt vmcnt(6)" ::: "memory");
        MIDBAR();
        DSLOAD_B(1); DOMFMA(1, 1);
        ENDBAR();
        STAGE_HT(nxt, 3, t + 1);
        MIDBAR();
        DSLOAD_A(0); DOMFMA(0, 1);
        ENDBAR();
    }
    {   // tail tile: drain 4 -> 2 -> 0
        int cur = (NT - 1) & 1;
        const char* _ab = (const char*)&lds[cur][0][0] + (wm2 << 11) + laneRd;
        const char* _bb = (const char*)&lds[cur][2][0] + (wn2 << 11) + laneRd;
        asm volatile("s_waitcnt vmcnt(4)" ::: "memory");
        MIDBAR();
        DSLOAD_A(0); DSLOAD_B(0); DOMFMA(0, 0);
        ENDBAR();
        asm volatile("s_waitcnt vmcnt(2)" ::: "memory");
        MIDBAR();
        DSLOAD_A(1); DOMFMA(1, 0);
        ENDBAR();
        asm volatile("s_waitcnt vmcnt(0)" ::: "memory");
        MIDBAR();
        DSLOAD_B(1); DOMFMA(1, 1);
        ENDBAR();
        DSLOAD_A(0); DOMFMA(0, 1);
    }

#pragma unroll
    for (int mg = 0; mg < 8; mg++) {
        long row0 = m0 + (long)(((mg >> 2) * 8 + (mg & 3) * 2 + wm2) * 16 + quad * 4);
#pragma unroll
        for (int ng = 0; ng < 4; ng++) {
            long col = n0 + ((ng >> 1) * 8 + (ng & 1) * 4 + wn2) * 16 + lrow;
            float bv = bias ? bias[col] : 0.f;
#pragma unroll
            for (int r = 0; r < 4; r++) {
                float v = acc[mg][ng][r] + bv;
                if (relu) v = fmaxf(v, 0.f);
                C[(row0 + r) * ldc + col] = f2b(v);
            }
        }
    }
#undef STAGE_HT
#undef DSLOAD_A
#undef DSLOAD_B
#undef DOMFMA
}

// ---------------- 128x256 2-phase counted-vmcnt bt-GEMM (for N=1024 shapes) --------
__global__ __launch_bounds__(512, 1) void gemm_btn(
    const u16* __restrict__ A, const u16* __restrict__ B,
    const float* __restrict__ bias, u16* __restrict__ C,
    int K, int lda, int ldb, int ldc, int relu, int nbx) {
    __shared__ __align__(16) u16 lds[2][3][8192];

    int nwg = gridDim.x;
    int id = blockIdx.x;
    int swz = (id & 7) * (nwg >> 3) + (id >> 3);
    int bx = swz % nbx, by = swz / nbx;
    long m0 = (long)by * 128, n0 = (long)bx * 256;

    int tid = threadIdx.x, lane = tid & 63, wave = tid >> 6;
    int lrow = lane & 15, quad = lane >> 4;
    int wm2 = wave >> 2;
    int wn2 = wave & 3;

    int laneRd = (lrow * 64 + quad * 16) ^ (((lrow >> 3) & 1) << 5);
    int Sl = (lane * 16) ^ (((lane >> 5) & 1) << 5);
    int wr = (Sl >> 6) & 15;
    int wb = Sl & 63;

    f32x4 acc[4][4];
#pragma unroll
    for (int i = 0; i < 4; i++)
#pragma unroll
        for (int j = 0; j < 4; j++) acc[i][j] = (f32x4){0.f, 0.f, 0.f, 0.f};
    bf16x8 af[4][2], bfr[2][2];

#define STAGE_HT(nb, ht, kt) do {                                              \
    const char* _gb = ((ht) == 0)                                              \
        ? (const char*)(A + m0 * lda)                                          \
        : (const char*)(B + (n0 + ((ht) - 1) * 128) * ldb);                    \
    long _ld = (long)(((ht) == 0) ? lda : ldb) * 2;                            \
    _Pragma("unroll")                                                          \
    for (int j = 0; j < 2; j++) {                                              \
        int sub = j * 8 + wave;                                                \
        int srow = (sub >> 1) * 16 + wr;                                       \
        int scolb = (sub & 1) * 64 + wb;                                       \
        gload16((const u16*)(_gb + (long)srow * _ld + (long)(kt) * 128 + scolb),\
                &lds[nb][ht][sub << 9]);                                       \
    }                                                                          \
} while (0)

#define DSLOAD_A() do {                                                        \
    _Pragma("unroll") for (int mi = 0; mi < 4; mi++)                           \
    _Pragma("unroll") for (int kk = 0; kk < 2; kk++)                           \
        af[mi][kk] = *(const bf16x8*)(_ab + ((mi * 4 + kk) << 10));            \
} while (0)

#define DSLOAD_B(qn) do {                                                      \
    const char* _p = _b0 + (qn) * 16384;                                       \
    _Pragma("unroll") for (int ni = 0; ni < 2; ni++)                           \
    _Pragma("unroll") for (int kk = 0; kk < 2; kk++)                           \
        bfr[ni][kk] = *(const bf16x8*)(_p + ((ni * 8 + kk) << 10));            \
} while (0)

#define DOMFMA(qn) do {                                                        \
    __builtin_amdgcn_s_setprio(1);                                             \
    _Pragma("unroll") for (int mi = 0; mi < 4; mi++)                           \
    _Pragma("unroll") for (int ni = 0; ni < 2; ni++)                           \
    _Pragma("unroll") for (int kk = 0; kk < 2; kk++)                           \
        acc[mi][(qn) * 2 + ni] =                                               \
            __builtin_amdgcn_mfma_f32_16x16x32_bf16(                           \
                af[mi][kk], bfr[ni][kk], acc[mi][(qn) * 2 + ni], 0, 0, 0);     \
    __builtin_amdgcn_s_setprio(0);                                             \
} while (0)

    int NT = K >> 6;
    STAGE_HT(0, 0, 0);
    STAGE_HT(0, 1, 0);
    STAGE_HT(0, 2, 0);

    for (int t = 0; t < NT - 1; t++) {
        int cur = t & 1, nxt = cur ^ 1;
        const char* _ab = (const char*)&lds[cur][0][0] + (wm2 << 11) + laneRd;
        const char* _b0 = (const char*)&lds[cur][1][0] + (wn2 << 11) + laneRd;
        STAGE_HT(nxt, 0, t + 1);
        asm volatile("s_waitcnt vmcnt(4)" ::: "memory");
        MIDBAR();
        DSLOAD_A(); DSLOAD_B(0); DOMFMA(0);
        ENDBAR();
        STAGE_HT(nxt, 1, t + 1);
        STAGE_HT(nxt, 2, t + 1);
        asm volatile("s_waitcnt vmcnt(6)" ::: "memory");
        MIDBAR();
        DSLOAD_B(1); DOMFMA(1);
        ENDBAR();
    }
    {   // tail tile: drain 2 -> 0
        int cur = (NT - 1) & 1;
        const char* _ab = (const char*)&lds[cur][0][0] + (wm2 << 11) + laneRd;
        const char* _b0 = (const char*)&lds[cur][1][0] + (wn2 << 11) + laneRd;
        asm volatile("s_waitcnt vmcnt(2)" ::: "memory");
        MIDBAR();
        DSLOAD_A(); DSLOAD_B(0); DOMFMA(0);
        ENDBAR();
        asm volatile("s_waitcnt vmcnt(0)" ::: "memory");
        MIDBAR();
        DSLOAD_B(1); DOMFMA(1);
    }

#pragma unroll
    for (int mi = 0; mi < 4; mi++) {
        long row0 = m0 + (long)((mi * 2 + wm2) * 16 + quad * 4);
#pragma unroll
        for (int ng = 0; ng < 4; ng++) {
            long col = n0 + ((ng >> 1) * 8 + (ng & 1) * 4 + wn2) * 16 + lrow;
            float bv = bias ? bias[col] : 0.f;
#pragma unroll
            for (int r = 0; r < 4; r++) {
                float v = acc[mi][ng][r] + bv;
                if (relu) v = fmaxf(v, 0.f);
                C[(row0 + r) * ldc + col] = f2b(v);
            }
        }
    }
#undef STAGE_HT
#undef DSLOAD_A
#undef DSLOAD_B
#undef DOMFMA
#undef MIDBAR
#undef ENDBAR
}

// ---------------- extract v from qkv (bf16), transposed per head ----------------
__global__ __launch_bounds__(256) void split_v(const u16* __restrict__ qkv,
                                               u16* __restrict__ vT) {
    __shared__ u16 tile[32][33];
    int bh = blockIdx.z;
    int b = bh >> 4, h = bh & 15;
    int s0 = blockIdx.x * 32;
    int d0 = blockIdx.y * 32;
    int tx = threadIdx.x & 31, ty = threadIdx.x >> 5;
    for (int i = ty; i < 32; i += 8)
        tile[i][tx] = qkv[((long)(b * 512 + s0 + i)) * 3072 + 2048 + h * 64 + d0 + tx];
    __syncthreads();
    for (int i = ty; i < 32; i += 8)
        vT[((long)bh * 64 + d0 + i) * 512 + s0 + tx] = tile[tx][i];
}

// ---------------- fused attention: scores + mask + softmax + PV ----------------
// Unified 64-key-chunk pipeline over a shared double-buffered LDS tile used
// first for K (8 QK chunks) then for V (8 PV chunks). Per chunk: ds_write
// regs->buf[nc&1]; prefetch next chunk to regs; ONE barrier; MFMA from buf.
// Dbuf parity makes write(nc+1) race-free vs MFMA(nc) (write targets buffer
// last read at nc-1, sealed by barrier nc). All MFMA operands come from LDS
// (round-2 proved direct-global fragments are a 16-line scatter, 24% slower).
// V chunk-0 loads issue before softmax so L2 latency hides under the VALU work.
__global__ __launch_bounds__(256) void attn_fused(
    const u16* __restrict__ qkv, const u16* __restrict__ vT,
    const int* __restrict__ mask, float* __restrict__ attnOut,
    u16* __restrict__ ctx) {
    __shared__ __align__(16) u16 s_k[2][64][72];      // K/V chunk staging (dbuf)
    __shared__ __align__(16) u16 s_p[4][16][68];      // per-wave P chunk (A-layout)
    __shared__ unsigned long long m_bits[8];

    // XCD-aware decode: xcd = id&7 owns bh === xcd (mod 8)
    int id = blockIdx.x;
    int t_ = id >> 3;
    int mtile = t_ & 7;
    int bh = (id & 7) + ((t_ >> 3) << 3);
    int b = bh >> 4, h = bh & 15;
    int tid = threadIdx.x, lane = tid & 63, wave = tid >> 6;
    int lrow = lane & 15, quad = lane >> 4;
    int m0 = mtile * 64;

    const u16* Qbase = qkv + (long)(b * 512) * 3072 + h * 64;
    const u16* Kbase = Qbase + 1024;
    const u16* vh = vT + (long)bh * 64 * 512;

    {   // mask bitmask: bit j of m_bits[c] = (mask[b*512 + c*64 + j] != 0)
        int i0 = wave * 64 + lane;
        unsigned long long bl0 = __ballot(mask[b * 512 + i0] != 0);
        if (lane == 0) m_bits[wave] = bl0;
        unsigned long long bl1 = __ballot(mask[b * 512 + 256 + i0] != 0);
        if (lane == 0) m_bits[4 + wave] = bl1;
    }

    // stage Q tile [64][64] into s_k[0]; prefetch K chunk 0 into regs
    int sr = tid >> 3, sc = (tid & 7) * 8;        // this thread's staging slot
    int sr2 = (256 + tid) >> 3, sc2 = sc;         // second slot (rows 32..63)
    *(uint4*)&s_k[0][sr][sc]  = *(const uint4*)(Qbase + (long)(m0 + sr) * 3072 + sc);
    *(uint4*)&s_k[0][sr2][sc2] = *(const uint4*)(Qbase + (long)(m0 + sr2) * 3072 + sc2);
    uint4 kreg[2];
    kreg[0] = *(const uint4*)(Kbase + (long)sr * 3072 + sc);
    kreg[1] = *(const uint4*)(Kbase + (long)sr2 * 3072 + sc2);
    __syncthreads();
    bf16x8 qf[2];
    qf[0] = *(const bf16x8*)&s_k[0][wave * 16 + lrow][0 + quad * 8];
    qf[1] = *(const bf16x8*)&s_k[0][wave * 16 + lrow][32 + quad * 8];
    __syncthreads();   // all waves have Q fragments before chunk 0 overwrites s_k[0]

    f32x4 sacc[32];
#pragma unroll
    for (int t = 0; t < 32; t++) sacc[t] = (f32x4){0.f, 0.f, 0.f, 0.f};

    // S = Q K^T over 8 chunks of 64 key-rows; 1 barrier/chunk, dbuf overlap
    for (int nc = 0; nc < 8; nc++) {
        int buf = nc & 1;
        *(uint4*)&s_k[buf][sr][sc]  = kreg[0];
        *(uint4*)&s_k[buf][sr2][sc2] = kreg[1];
        if (nc < 7) {
            kreg[0] = *(const uint4*)(Kbase + (long)((nc + 1) * 64 + sr) * 3072 + sc);
            kreg[1] = *(const uint4*)(Kbase + (long)((nc + 1) * 64 + sr2) * 3072 + sc2);
        }
        __syncthreads();
#pragma unroll
        for (int ni = 0; ni < 4; ni++) {
            bf16x8 b0 = *(const bf16x8*)&s_k[buf][ni * 16 + lrow][0 + quad * 8];
            bf16x8 b1 = *(const bf16x8*)&s_k[buf][ni * 16 + lrow][32 + quad * 8];
            int t = nc * 4 + ni;
            sacc[t] = __builtin_amdgcn_mfma_f32_16x16x32_bf16(qf[0], b0, sacc[t], 0, 0, 0);
            sacc[t] = __builtin_amdgcn_mfma_f32_16x16x32_bf16(qf[1], b1, sacc[t], 0, 0, 0);
        }
    }

    // prefetch V chunk 0 (L2 latency hides under softmax VALU below)
    uint4 vreg[2];
    vreg[0] = *(const uint4*)(vh + (long)sr * 512 + sc);
    vreg[1] = *(const uint4*)(vh + (long)sr2 * 512 + sc2);

    // mask + scale; lane holds rows quad*4+r, cols t*16+lrow
    float mx[4] = {-3.0e38f, -3.0e38f, -3.0e38f, -3.0e38f};
#pragma unroll
    for (int t = 0; t < 32; t++) {
        int col = t * 16 + lrow;
        int on = (int)((m_bits[col >> 6] >> (col & 63)) & 1ull);
#pragma unroll
        for (int r = 0; r < 4; r++) {
            float s = on ? sacc[t][r] * 0.125f : -1e9f;
            sacc[t][r] = s;
            mx[r] = fmaxf(mx[r], s);
        }
    }
#pragma unroll
    for (int off = 1; off < 16; off <<= 1)
#pragma unroll
        for (int r = 0; r < 4; r++) mx[r] = fmaxf(mx[r], __shfl_xor(mx[r], off));
    float sm[4] = {0.f, 0.f, 0.f, 0.f};
#pragma unroll
    for (int t = 0; t < 32; t++)
#pragma unroll
        for (int r = 0; r < 4; r++) {
            float e = __expf(sacc[t][r] - mx[r]);
            sacc[t][r] = e;
            sm[r] += e;
        }
#pragma unroll
    for (int off = 1; off < 16; off <<= 1)
#pragma unroll
        for (int r = 0; r < 4; r++) sm[r] += __shfl_xor(sm[r], off);
#pragma unroll
    for (int r = 0; r < 4; r++) sm[r] = 1.0f / sm[r];
#pragma unroll
    for (int t = 0; t < 32; t++)
#pragma unroll
        for (int r = 0; r < 4; r++) sacc[t][r] *= sm[r];

    // PV over 8 chunks of 64 keys; V staged through the same dbuf, 1 barrier/chunk.
    // Safe vs QK tail: PV chunk 0 writes s_k[0]; last QK MFMA (chunk 7) read s_k[1].
    f32x4 cacc[4];
#pragma unroll
    for (int ni = 0; ni < 4; ni++) cacc[ni] = (f32x4){0.f, 0.f, 0.f, 0.f};
    int prow = lane >> 4;      // row group for prob write
    int pseg = lane & 15;      // float4 index within 64-col chunk

    for (int nc = 0; nc < 8; nc++) {
        int buf = nc & 1;
        *(uint4*)&s_k[buf][sr][sc]  = vreg[0];
        *(uint4*)&s_k[buf][sr2][sc2] = vreg[1];
        if (nc < 7) {
            vreg[0] = *(const uint4*)(vh + (long)sr * 512 + (nc + 1) * 64 + sc);
            vreg[1] = *(const uint4*)(vh + (long)sr2 * 512 + (nc + 1) * 64 + sc2);
        }
        // transpose this wave's P chunk into s_p (wave-private, no barrier needed)
#pragma unroll
        for (int t2 = 0; t2 < 4; t2++) {
            int t = nc * 4 + t2;
#pragma unroll
            for (int r = 0; r < 4; r++)
                s_p[wave][quad * 4 + r][t2 * 16 + lrow] = f2b(sacc[t][r]);
        }
        __syncthreads();

        // coalesced probs write-out of this wave's 16x64 chunk
        {
            float* abase = attnOut + (long)bh * 512 * 512
                         + (long)(m0 + wave * 16) * 512 + nc * 64;
#pragma unroll
            for (int i = 0; i < 4; i++) {
                int row = i * 4 + prow;
                uint2 pv = *(const uint2*)&s_p[wave][row][pseg * 4];
                float4 o;
                o.x = b2f_u32(pv.x << 16);
                o.y = b2f_u32(pv.x & 0xffff0000u);
                o.z = b2f_u32(pv.y << 16);
                o.w = b2f_u32(pv.y & 0xffff0000u);
                *(float4*)(abase + (long)row * 512 + pseg * 4) = o;
            }
        }

#pragma unroll
        for (int kk = 0; kk < 2; kk++) {
            bf16x8 pf = *(const bf16x8*)&s_p[wave][lrow][kk * 32 + quad * 8];
#pragma unroll
            for (int ni = 0; ni < 4; ni++) {
                bf16x8 vf = *(const bf16x8*)&s_k[buf][ni * 16 + lrow][kk * 32 + quad * 8];
                cacc[ni] = __builtin_amdgcn_mfma_f32_16x16x32_bf16(pf, vf, cacc[ni], 0, 0, 0);
            }
        }
    }

    u16* crow = ctx + (long)(b * 512 + m0 + wave * 16 + quad * 4) * 1024 + h * 64 + lrow;
#pragma unroll
    for (int ni = 0; ni < 4; ni++)
#pragma unroll
        for (int r = 0; r < 4; r++) crow[(long)r * 1024 + ni * 16] = f2b(cacc[ni][r]);
}

// ---------------- out = LayerNorm(a + r) * g + beta ----------------
__global__ __launch_bounds__(256) void add_ln(const u16* __restrict__ a,
                                              const void* __restrict__ r, int r_fp32,
                                              const float* __restrict__ g,
                                              const float* __restrict__ beta,
                                              void* __restrict__ out, int out_fp32) {
    long row = blockIdx.x;
    const u16* pa = a + row * 1024;
    int tid = threadIdx.x;
    float v[4];
    float sum = 0.f, sq = 0.f;
#pragma unroll
    for (int j = 0; j < 4; j++) {
        int c = tid + j * 256;
        float rv = r_fp32 ? ((const float*)r)[row * 1024 + c]
                          : b2f(((const u16*)r)[row * 1024 + c]);
        float x = b2f(pa[c]) + rv;
        v[j] = x;
        sum += x;
        sq += x * x;
    }
#pragma unroll
    for (int off = 32; off >= 1; off >>= 1) {
        sum += __shfl_xor(sum, off);
        sq += __shfl_xor(sq, off);
    }
    __shared__ float red[2][4];
    int wave = tid >> 6, lane = tid & 63;
    if (lane == 0) { red[0][wave] = sum; red[1][wave] = sq; }
    __syncthreads();
    sum = red[0][0] + red[0][1] + red[0][2] + red[0][3];
    sq = red[1][0] + red[1][1] + red[1][2] + red[1][3];
    float mu = sum * (1.f / 1024.f);
    float var = sq * (1.f / 1024.f) - mu * mu;
    float rstd = rsqrtf(var + 1e-6f);
#pragma unroll
    for (int j = 0; j < 4; j++) {
        int c = tid + j * 256;
        float y = (v[j] - mu) * rstd * g[c] + beta[c];
        if (out_fp32) ((float*)out)[row * 1024 + c] = y;
        else ((u16*)out)[row * 1024 + c] = f2b(y);
    }
}

extern "C" void kernel_launch(void* const* d_in, const int* in_sizes, int n_in,
                              void* d_out, int out_size, void* d_ws, size_t ws_size,
                              hipStream_t stream) {
    const float* x   = (const float*)d_in[0];
    const float* Wq  = (const float*)d_in[1];
    const float* bq  = (const float*)d_in[2];
    const float* Wk  = (const float*)d_in[3];
    const float* bk  = (const float*)d_in[4];
    const float* Wv  = (const float*)d_in[5];
    const float* bv  = (const float*)d_in[6];
    const float* Wo  = (const float*)d_in[7];
    const float* bo  = (const float*)d_in[8];
    const float* g1  = (const float*)d_in[9];
    const float* be1 = (const float*)d_in[10];
    const float* w1  = (const float*)d_in[11];
    const float* b1  = (const float*)d_in[12];
    const float* w2  = (const float*)d_in[13];
    const float* b2  = (const float*)d_in[14];
    const float* g2  = (const float*)d_in[15];
    const float* be2 = (const float*)d_in[16];
    const int* mask  = (const int*)d_in[17];

    float* out = (float*)d_out;                   // [8192][1024] fp32
    float* attn = out + (long)8192 * 1024;        // [256][512][512] fp32

    char* w = (char*)d_ws;
    auto alloc = [&](size_t bytes) {
        char* p = w;
        w += (bytes + 255) & ~(size_t)255;
        return p;
    };
    u16* WqkvT = (u16*)alloc(3072L * 1024 * 2);
    u16* WoT   = (u16*)alloc(1024L * 1024 * 2);
    u16* w1T   = (u16*)alloc(4096L * 1024 * 2);
    u16* w2T   = (u16*)alloc(1024L * 4096 * 2);
    float* bqkv = (float*)alloc(3072L * 4);
    u16* xb    = (u16*)alloc(8192L * 1024 * 2);
    char* P1 = alloc(8192L * 4096 * 2);  // qkv (48MB) -> ff (64MB)
    u16* qkv = (u16*)P1;
    u16* ff  = (u16*)P1;
    char* P2 = alloc(256L * 64 * 512 * 2);  // vT -> y2
    u16* vT = (u16*)P2;
    u16* y2 = (u16*)P2;
    u16* ctx = (u16*)alloc(8192L * 1024 * 2);
    u16* x1  = (u16*)alloc(8192L * 1024 * 2);
    u16* y   = (u16*)alloc(8192L * 1024 * 2);

    dim3 blk(256);

    transpose_f2b<<<dim3(32, 32), blk, 0, stream>>>(Wq, WqkvT, 1024, 1024);
    transpose_f2b<<<dim3(32, 32), blk, 0, stream>>>(Wk, WqkvT + 1024L * 1024, 1024, 1024);
    transpose_f2b<<<dim3(32, 32), blk, 0, stream>>>(Wv, WqkvT + 2048L * 1024, 1024, 1024);
    transpose_f2b<<<dim3(32, 32), blk, 0, stream>>>(Wo, WoT, 1024, 1024);
    transpose_f2b<<<dim3(128, 32), blk, 0, stream>>>(w1, w1T, 1024, 4096);
    transpose_f2b<<<dim3(32, 128), blk, 0, stream>>>(w2, w2T, 4096, 1024);
    concat3<<<12, blk, 0, stream>>>(bq, bk, bv, bqkv);
    conv_f2b<<<8192, blk, 0, stream>>>(x, xb, 8192L * 1024);

    // qkv = xb @ [Wq|Wk|Wv]^T + bqkv   (M=8192, N=3072, K=1024) — 256^2 8-phase
    gemm_bt256<<<dim3(384), dim3(512), 0, stream>>>(
        xb, WqkvT, bqkv, qkv, 8192, 3072, 1024, 1024, 1024, 3072, 0, 12);

    split_v<<<dim3(16, 2, 256), blk, 0, stream>>>(qkv, vT);

    // fused attention: probs -> attn (fp32), ctx (bf16 merged heads)
    attn_fused<<<dim3(2048), blk, 0, stream>>>(qkv, vT, mask, attn, ctx);

    // y = ctx @ Wo^T + bo   (M=8192, N=1024, K=1024) — 128x256 2-phase, 256 blocks
    gemm_btn<<<dim3(256), dim3(512), 0, stream>>>(
        ctx, WoT, bo, y, 1024, 1024, 1024, 1024, 0, 4);

    // x1 = LN(y + x)
    add_ln<<<8192, blk, 0, stream>>>(y, x, 1, g1, be1, x1, 0);

    // ff = relu(x1 @ w1^T + b1)   (M=8192, N=4096, K=1024) — 256^2 8-phase
    gemm_bt256<<<dim3(512), dim3(512), 0, stream>>>(
        x1, w1T, b1, ff, 8192, 4096, 1024, 1024, 1024, 4096, 1, 16);

    // y2 = ff @ w2^T + b2   (M=8192, N=1024, K=4096) — 128x256 2-phase, 256 blocks
    gemm_btn<<<dim3(256), dim3(512), 0, stream>>>(
        ff, w2T, b2, y2, 4096, 4096, 4096, 1024, 0, 4);

    // out = LN(y2 + x1)
    add_ln<<<8192, blk, 0, stream>>>(y2, x1, 0, g2, be2, out, 1);
}

// Round 6
// 795.472 us; speedup vs baseline: 1.0937x; 1.0217x over previous
//
#include <hip/hip_runtime.h>
#include <hip/hip_bf16.h>

typedef unsigned short u16;
typedef __bf16 bf16x8 __attribute__((ext_vector_type(8)));
typedef float f32x4 __attribute__((ext_vector_type(4)));

static __device__ __forceinline__ float b2f(u16 x) {
    unsigned int u = ((unsigned int)x) << 16;
    float f; __builtin_memcpy(&f, &u, 4); return f;
}
static __device__ __forceinline__ float b2f_u32(unsigned int u) {
    float f; __builtin_memcpy(&f, &u, 4); return f;
}
static __device__ __forceinline__ u16 f2b(float f) {
    unsigned int u; __builtin_memcpy(&u, &f, 4);
    unsigned int lsb = (u >> 16) & 1u;
    u += 0x7fffu + lsb;
    return (u16)(u >> 16);
}

// async 16B global->LDS (wave-uniform LDS base + lane*16)
static __device__ __forceinline__ void gload16(const u16* g, u16* l) {
    __builtin_amdgcn_global_load_lds(
        (const __attribute__((address_space(1))) unsigned int*)g,
        (__attribute__((address_space(3))) unsigned int*)l, 16, 0, 0);
}

// ---------------- transpose+convert: src fp32 [R][C] -> dst bf16 [C][R] ----------------
__global__ __launch_bounds__(256) void transpose_f2b(const float* __restrict__ src,
                                                     u16* __restrict__ dst,
                                                     int R, int C) {
    __shared__ u16 tile[32][33];
    int c0 = blockIdx.x * 32, r0 = blockIdx.y * 32;
    int tx = threadIdx.x & 31, ty = threadIdx.x >> 5;
    for (int i = ty; i < 32; i += 8) {
        int r = r0 + i, c = c0 + tx;
        tile[i][tx] = (r < R && c < C) ? f2b(src[(long)r * C + c]) : (u16)0;
    }
    __syncthreads();
    for (int i = ty; i < 32; i += 8) {
        int c = c0 + i, r = r0 + tx;
        if (c < C && r < R) dst[(long)c * R + r] = tile[tx][i];
    }
}

// ---------------- concat 3 fp32 bias vectors of 1024 ----------------
__global__ __launch_bounds__(256) void concat3(const float* a, const float* b, const float* c,
                                               float* out) {
    int i = blockIdx.x * 256 + threadIdx.x;
    if (i < 1024) out[i] = a[i];
    else if (i < 2048) out[i] = b[i - 1024];
    else if (i < 3072) out[i] = c[i - 2048];
}

// ---------------- fp32 -> bf16 bulk convert ----------------
__global__ __launch_bounds__(256) void conv_f2b(const float* __restrict__ src,
                                                u16* __restrict__ dst, long n) {
    long i = ((long)blockIdx.x * 256 + threadIdx.x) * 4;
    if (i >= n) return;
    float4 f = *(const float4*)(src + i);
    ushort4 o;
    o.x = f2b(f.x); o.y = f2b(f.y); o.z = f2b(f.z); o.w = f2b(f.w);
    *(ushort4*)(dst + i) = o;
}

// ---------------- 256x256 8-phase bt-GEMM (T2 swizzle + T3/T4 counted vmcnt + T5) ----
__global__ __launch_bounds__(512, 1) void gemm_bt256(
    const u16* __restrict__ A, const u16* __restrict__ B,
    const float* __restrict__ bias, u16* __restrict__ C,
    int M, int N, int K, int lda, int ldb, int ldc, int relu, int nbx) {
    __shared__ __align__(16) u16 lds[2][4][8192];

    int nwg = gridDim.x;
    int id = blockIdx.x;
    int swz = (id & 7) * (nwg >> 3) + (id >> 3);   // nwg % 8 == 0 at all call sites
    int bx = swz % nbx, by = swz / nbx;
    long m0 = (long)by * 256, n0 = (long)bx * 256;

    int tid = threadIdx.x, lane = tid & 63, wave = tid >> 6;
    int lrow = lane & 15, quad = lane >> 4;
    int wm2 = wave >> 2;        // M-half of wave (interleaved 16-row slabs)
    int wn2 = wave & 3;         // N-group of wave (interleaved 16-col slabs)

    int laneRd = (lrow * 64 + quad * 16) ^ (((lrow >> 3) & 1) << 5);
    int Sl = (lane * 16) ^ (((lane >> 5) & 1) << 5);
    int wr = (Sl >> 6) & 15;
    int wb = Sl & 63;

    f32x4 acc[8][4];
#pragma unroll
    for (int i = 0; i < 8; i++)
#pragma unroll
        for (int j = 0; j < 4; j++) acc[i][j] = (f32x4){0.f, 0.f, 0.f, 0.f};
    bf16x8 af[4][2], bfr[2][2];

#define STAGE_HT(nb, ht, kt) do {                                              \
    const char* _gb = ((ht) < 2)                                               \
        ? (const char*)(A + (m0 + (ht) * 128) * lda)                           \
        : (const char*)(B + (n0 + ((ht) - 2) * 128) * ldb);                    \
    long _ld = (long)(((ht) < 2) ? lda : ldb) * 2;                             \
    _Pragma("unroll")                                                          \
    for (int j = 0; j < 2; j++) {                                              \
        int sub = j * 8 + wave;                                                \
        int srow = (sub >> 1) * 16 + wr;                                       \
        int scolb = (sub & 1) * 64 + wb;                                       \
        gload16((const u16*)(_gb + (long)srow * _ld + (long)(kt) * 128 + scolb),\
                &lds[nb][ht][sub << 9]);                                       \
    }                                                                          \
} while (0)

#define DSLOAD_A(qm) do {                                                      \
    const char* _p = _ab + ((qm) << 14);                                       \
    _Pragma("unroll") for (int mi = 0; mi < 4; mi++)                           \
    _Pragma("unroll") for (int kk = 0; kk < 2; kk++)                           \
        af[mi][kk] = *(const bf16x8*)(_p + ((mi * 4 + kk) << 10));             \
} while (0)

#define DSLOAD_B(qn) do {                                                      \
    const char* _p = _bb + ((qn) << 14);                                       \
    _Pragma("unroll") for (int ni = 0; ni < 2; ni++)                           \
    _Pragma("unroll") for (int kk = 0; kk < 2; kk++)                           \
        bfr[ni][kk] = *(const bf16x8*)(_p + ((ni * 8 + kk) << 10));            \
} while (0)

#define DOMFMA(qm, qn) do {                                                    \
    __builtin_amdgcn_s_setprio(1);                                             \
    _Pragma("unroll") for (int mi = 0; mi < 4; mi++)                           \
    _Pragma("unroll") for (int ni = 0; ni < 2; ni++)                           \
    _Pragma("unroll") for (int kk = 0; kk < 2; kk++)                           \
        acc[(qm) * 4 + mi][(qn) * 2 + ni] =                                    \
            __builtin_amdgcn_mfma_f32_16x16x32_bf16(                           \
                af[mi][kk], bfr[ni][kk], acc[(qm) * 4 + mi][(qn) * 2 + ni],    \
                0, 0, 0);                                                      \
    __builtin_amdgcn_s_setprio(0);                                             \
} while (0)

#define MIDBAR()  do { __builtin_amdgcn_s_barrier(); __builtin_amdgcn_sched_barrier(0); } while (0)
#define ENDBAR()  do { __builtin_amdgcn_sched_barrier(0); __builtin_amdgcn_s_barrier(); } while (0)

    int NT = K >> 6;
    STAGE_HT(0, 0, 0);
    STAGE_HT(0, 2, 0);
    STAGE_HT(0, 1, 0);
    STAGE_HT(0, 3, 0);

    for (int t = 0; t < NT - 1; t++) {
        int cur = t & 1, nxt = cur ^ 1;
        const char* _ab = (const char*)&lds[cur][0][0] + (wm2 << 11) + laneRd;
        const char* _bb = (const char*)&lds[cur][2][0] + (wn2 << 11) + laneRd;
        STAGE_HT(nxt, 0, t + 1);
        asm volatile("s_waitcnt vmcnt(6)" ::: "memory");
        MIDBAR();
        DSLOAD_A(0); DSLOAD_B(0); DOMFMA(0, 0);
        ENDBAR();
        STAGE_HT(nxt, 2, t + 1);
        asm volatile("s_waitcnt vmcnt(6)" ::: "memory");
        MIDBAR();
        DSLOAD_A(1); DOMFMA(1, 0);
        ENDBAR();
        STAGE_HT(nxt, 1, t + 1);
        asm volatile("s_waitcnt vmcnt(6)" ::: "memory");
        MIDBAR();
        DSLOAD_B(1); DOMFMA(1, 1);
        ENDBAR();
        STAGE_HT(nxt, 3, t + 1);
        MIDBAR();
        DSLOAD_A(0); DOMFMA(0, 1);
        ENDBAR();
    }
    {   // tail tile: drain 4 -> 2 -> 0
        int cur = (NT - 1) & 1;
        const char* _ab = (const char*)&lds[cur][0][0] + (wm2 << 11) + laneRd;
        const char* _bb = (const char*)&lds[cur][2][0] + (wn2 << 11) + laneRd;
        asm volatile("s_waitcnt vmcnt(4)" ::: "memory");
        MIDBAR();
        DSLOAD_A(0); DSLOAD_B(0); DOMFMA(0, 0);
        ENDBAR();
        asm volatile("s_waitcnt vmcnt(2)" ::: "memory");
        MIDBAR();
        DSLOAD_A(1); DOMFMA(1, 0);
        ENDBAR();
        asm volatile("s_waitcnt vmcnt(0)" ::: "memory");
        MIDBAR();
        DSLOAD_B(1); DOMFMA(1, 1);
        ENDBAR();
        DSLOAD_A(0); DOMFMA(0, 1);
    }

#pragma unroll
    for (int mg = 0; mg < 8; mg++) {
        long row0 = m0 + (long)(((mg >> 2) * 8 + (mg & 3) * 2 + wm2) * 16 + quad * 4);
#pragma unroll
        for (int ng = 0; ng < 4; ng++) {
            long col = n0 + ((ng >> 1) * 8 + (ng & 1) * 4 + wn2) * 16 + lrow;
            float bv = bias ? bias[col] : 0.f;
#pragma unroll
            for (int r = 0; r < 4; r++) {
                float v = acc[mg][ng][r] + bv;
                if (relu) v = fmaxf(v, 0.f);
                C[(row0 + r) * ldc + col] = f2b(v);
            }
        }
    }
#undef STAGE_HT
#undef DSLOAD_A
#undef DSLOAD_B
#undef DOMFMA
}

// ---------------- split-K=2 256x256 8-phase bt-GEMM, fp32 partial output -----------
// Same verified 8-phase schedule; id&1 selects K-half; partials go to
// Cf + split*csize; combine happens in add_ln2 (free: it already reads 2 terms).
__global__ __launch_bounds__(512, 1) void gemm_sk256(
    const u16* __restrict__ A, const u16* __restrict__ B,
    float* __restrict__ Cf,
    int Ksplit, int lda, int ldb, int ldc, int nbx, long csize) {
    __shared__ __align__(16) u16 lds[2][4][8192];

    int id = blockIdx.x;
    int sp = id & 1;
    int id2 = id >> 1;
    int nwg2 = gridDim.x >> 1;
    int swz = (id2 & 7) * (nwg2 >> 3) + (id2 >> 3);
    int bx = swz % nbx, by = swz / nbx;
    long m0 = (long)by * 256, n0 = (long)bx * 256;

    A += (long)sp * Ksplit;
    B += (long)sp * Ksplit;
    Cf += (long)sp * csize;

    int tid = threadIdx.x, lane = tid & 63, wave = tid >> 6;
    int lrow = lane & 15, quad = lane >> 4;
    int wm2 = wave >> 2;
    int wn2 = wave & 3;

    int laneRd = (lrow * 64 + quad * 16) ^ (((lrow >> 3) & 1) << 5);
    int Sl = (lane * 16) ^ (((lane >> 5) & 1) << 5);
    int wr = (Sl >> 6) & 15;
    int wb = Sl & 63;

    f32x4 acc[8][4];
#pragma unroll
    for (int i = 0; i < 8; i++)
#pragma unroll
        for (int j = 0; j < 4; j++) acc[i][j] = (f32x4){0.f, 0.f, 0.f, 0.f};
    bf16x8 af[4][2], bfr[2][2];

#define STAGE_HT(nb, ht, kt) do {                                              \
    const char* _gb = ((ht) < 2)                                               \
        ? (const char*)(A + (m0 + (ht) * 128) * lda)                           \
        : (const char*)(B + (n0 + ((ht) - 2) * 128) * ldb);                    \
    long _ld = (long)(((ht) < 2) ? lda : ldb) * 2;                             \
    _Pragma("unroll")                                                          \
    for (int j = 0; j < 2; j++) {                                              \
        int sub = j * 8 + wave;                                                \
        int srow = (sub >> 1) * 16 + wr;                                       \
        int scolb = (sub & 1) * 64 + wb;                                       \
        gload16((const u16*)(_gb + (long)srow * _ld + (long)(kt) * 128 + scolb),\
                &lds[nb][ht][sub << 9]);                                       \
    }                                                                          \
} while (0)

#define DSLOAD_A(qm) do {                                                      \
    const char* _p = _ab + ((qm) << 14);                                       \
    _Pragma("unroll") for (int mi = 0; mi < 4; mi++)                           \
    _Pragma("unroll") for (int kk = 0; kk < 2; kk++)                           \
        af[mi][kk] = *(const bf16x8*)(_p + ((mi * 4 + kk) << 10));             \
} while (0)

#define DSLOAD_B(qn) do {                                                      \
    const char* _p = _bb + ((qn) << 14);                                       \
    _Pragma("unroll") for (int ni = 0; ni < 2; ni++)                           \
    _Pragma("unroll") for (int kk = 0; kk < 2; kk++)                           \
        bfr[ni][kk] = *(const bf16x8*)(_p + ((ni * 8 + kk) << 10));            \
} while (0)

#define DOMFMA(qm, qn) do {                                                    \
    __builtin_amdgcn_s_setprio(1);                                             \
    _Pragma("unroll") for (int mi = 0; mi < 4; mi++)                           \
    _Pragma("unroll") for (int ni = 0; ni < 2; ni++)                           \
    _Pragma("unroll") for (int kk = 0; kk < 2; kk++)                           \
        acc[(qm) * 4 + mi][(qn) * 2 + ni] =                                    \
            __builtin_amdgcn_mfma_f32_16x16x32_bf16(                           \
                af[mi][kk], bfr[ni][kk], acc[(qm) * 4 + mi][(qn) * 2 + ni],    \
                0, 0, 0);                                                      \
    __builtin_amdgcn_s_setprio(0);                                             \
} while (0)

    int NT = Ksplit >> 6;
    STAGE_HT(0, 0, 0);
    STAGE_HT(0, 2, 0);
    STAGE_HT(0, 1, 0);
    STAGE_HT(0, 3, 0);

    for (int t = 0; t < NT - 1; t++) {
        int cur = t & 1, nxt = cur ^ 1;
        const char* _ab = (const char*)&lds[cur][0][0] + (wm2 << 11) + laneRd;
        const char* _bb = (const char*)&lds[cur][2][0] + (wn2 << 11) + laneRd;
        STAGE_HT(nxt, 0, t + 1);
        asm volatile("s_waitcnt vmcnt(6)" ::: "memory");
        MIDBAR();
        DSLOAD_A(0); DSLOAD_B(0); DOMFMA(0, 0);
        ENDBAR();
        STAGE_HT(nxt, 2, t + 1);
        asm volatile("s_waitcnt vmcnt(6)" ::: "memory");
        MIDBAR();
        DSLOAD_A(1); DOMFMA(1, 0);
        ENDBAR();
        STAGE_HT(nxt, 1, t + 1);
        asm volatile("s_waitcnt vmcnt(6)" ::: "memory");
        MIDBAR();
        DSLOAD_B(1); DOMFMA(1, 1);
        ENDBAR();
        STAGE_HT(nxt, 3, t + 1);
        MIDBAR();
        DSLOAD_A(0); DOMFMA(0, 1);
        ENDBAR();
    }
    {   // tail tile: drain 4 -> 2 -> 0
        int cur = (NT - 1) & 1;
        const char* _ab = (const char*)&lds[cur][0][0] + (wm2 << 11) + laneRd;
        const char* _bb = (const char*)&lds[cur][2][0] + (wn2 << 11) + laneRd;
        asm volatile("s_waitcnt vmcnt(4)" ::: "memory");
        MIDBAR();
        DSLOAD_A(0); DSLOAD_B(0); DOMFMA(0, 0);
        ENDBAR();
        asm volatile("s_waitcnt vmcnt(2)" ::: "memory");
        MIDBAR();
        DSLOAD_A(1); DOMFMA(1, 0);
        ENDBAR();
        asm volatile("s_waitcnt vmcnt(0)" ::: "memory");
        MIDBAR();
        DSLOAD_B(1); DOMFMA(1, 1);
        ENDBAR();
        DSLOAD_A(0); DOMFMA(0, 1);
    }

#pragma unroll
    for (int mg = 0; mg < 8; mg++) {
        long row0 = m0 + (long)(((mg >> 2) * 8 + (mg & 3) * 2 + wm2) * 16 + quad * 4);
#pragma unroll
        for (int ng = 0; ng < 4; ng++) {
            long col = n0 + ((ng >> 1) * 8 + (ng & 1) * 4 + wn2) * 16 + lrow;
#pragma unroll
            for (int r = 0; r < 4; r++)
                Cf[(row0 + r) * ldc + col] = acc[mg][ng][r];
        }
    }
#undef STAGE_HT
#undef DSLOAD_A
#undef DSLOAD_B
#undef DOMFMA
}

// ---------------- 128x256 2-phase counted-vmcnt bt-GEMM (for Wo) --------
__global__ __launch_bounds__(512, 1) void gemm_btn(
    const u16* __restrict__ A, const u16* __restrict__ B,
    const float* __restrict__ bias, u16* __restrict__ C,
    int K, int lda, int ldb, int ldc, int relu, int nbx) {
    __shared__ __align__(16) u16 lds[2][3][8192];

    int nwg = gridDim.x;
    int id = blockIdx.x;
    int swz = (id & 7) * (nwg >> 3) + (id >> 3);
    int bx = swz % nbx, by = swz / nbx;
    long m0 = (long)by * 128, n0 = (long)bx * 256;

    int tid = threadIdx.x, lane = tid & 63, wave = tid >> 6;
    int lrow = lane & 15, quad = lane >> 4;
    int wm2 = wave >> 2;
    int wn2 = wave & 3;

    int laneRd = (lrow * 64 + quad * 16) ^ (((lrow >> 3) & 1) << 5);
    int Sl = (lane * 16) ^ (((lane >> 5) & 1) << 5);
    int wr = (Sl >> 6) & 15;
    int wb = Sl & 63;

    f32x4 acc[4][4];
#pragma unroll
    for (int i = 0; i < 4; i++)
#pragma unroll
        for (int j = 0; j < 4; j++) acc[i][j] = (f32x4){0.f, 0.f, 0.f, 0.f};
    bf16x8 af[4][2], bfr[2][2];

#define STAGE_HT(nb, ht, kt) do {                                              \
    const char* _gb = ((ht) == 0)                                              \
        ? (const char*)(A + m0 * lda)                                          \
        : (const char*)(B + (n0 + ((ht) - 1) * 128) * ldb);                    \
    long _ld = (long)(((ht) == 0) ? lda : ldb) * 2;                            \
    _Pragma("unroll")                                                          \
    for (int j = 0; j < 2; j++) {                                              \
        int sub = j * 8 + wave;                                                \
        int srow = (sub >> 1) * 16 + wr;                                       \
        int scolb = (sub & 1) * 64 + wb;                                       \
        gload16((const u16*)(_gb + (long)srow * _ld + (long)(kt) * 128 + scolb),\
                &lds[nb][ht][sub << 9]);                                       \
    }                                                                          \
} while (0)

#define DSLOAD_A() do {                                                        \
    _Pragma("unroll") for (int mi = 0; mi < 4; mi++)                           \
    _Pragma("unroll") for (int kk = 0; kk < 2; kk++)                           \
        af[mi][kk] = *(const bf16x8*)(_ab + ((mi * 4 + kk) << 10));            \
} while (0)

#define DSLOAD_B(qn) do {                                                      \
    const char* _p = _b0 + (qn) * 16384;                                       \
    _Pragma("unroll") for (int ni = 0; ni < 2; ni++)                           \
    _Pragma("unroll") for (int kk = 0; kk < 2; kk++)                           \
        bfr[ni][kk] = *(const bf16x8*)(_p + ((ni * 8 + kk) << 10));            \
} while (0)

#define DOMFMA(qn) do {                                                        \
    __builtin_amdgcn_s_setprio(1);                                             \
    _Pragma("unroll") for (int mi = 0; mi < 4; mi++)                           \
    _Pragma("unroll") for (int ni = 0; ni < 2; ni++)                           \
    _Pragma("unroll") for (int kk = 0; kk < 2; kk++)                           \
        acc[mi][(qn) * 2 + ni] =                                               \
            __builtin_amdgcn_mfma_f32_16x16x32_bf16(                           \
                af[mi][kk], bfr[ni][kk], acc[mi][(qn) * 2 + ni], 0, 0, 0);     \
    __builtin_amdgcn_s_setprio(0);                                             \
} while (0)

    int NT = K >> 6;
    STAGE_HT(0, 0, 0);
    STAGE_HT(0, 1, 0);
    STAGE_HT(0, 2, 0);

    for (int t = 0; t < NT - 1; t++) {
        int cur = t & 1, nxt = cur ^ 1;
        const char* _ab = (const char*)&lds[cur][0][0] + (wm2 << 11) + laneRd;
        const char* _b0 = (const char*)&lds[cur][1][0] + (wn2 << 11) + laneRd;
        STAGE_HT(nxt, 0, t + 1);
        asm volatile("s_waitcnt vmcnt(4)" ::: "memory");
        MIDBAR();
        DSLOAD_A(); DSLOAD_B(0); DOMFMA(0);
        ENDBAR();
        STAGE_HT(nxt, 1, t + 1);
        STAGE_HT(nxt, 2, t + 1);
        asm volatile("s_waitcnt vmcnt(6)" ::: "memory");
        MIDBAR();
        DSLOAD_B(1); DOMFMA(1);
        ENDBAR();
    }
    {   // tail tile: drain 2 -> 0
        int cur = (NT - 1) & 1;
        const char* _ab = (const char*)&lds[cur][0][0] + (wm2 << 11) + laneRd;
        const char* _b0 = (const char*)&lds[cur][1][0] + (wn2 << 11) + laneRd;
        asm volatile("s_waitcnt vmcnt(2)" ::: "memory");
        MIDBAR();
        DSLOAD_A(); DSLOAD_B(0); DOMFMA(0);
        ENDBAR();
        asm volatile("s_waitcnt vmcnt(0)" ::: "memory");
        MIDBAR();
        DSLOAD_B(1); DOMFMA(1);
    }

#pragma unroll
    for (int mi = 0; mi < 4; mi++) {
        long row0 = m0 + (long)((mi * 2 + wm2) * 16 + quad * 4);
#pragma unroll
        for (int ng = 0; ng < 4; ng++) {
            long col = n0 + ((ng >> 1) * 8 + (ng & 1) * 4 + wn2) * 16 + lrow;
            float bv = bias ? bias[col] : 0.f;
#pragma unroll
            for (int r = 0; r < 4; r++) {
                float v = acc[mi][ng][r] + bv;
                if (relu) v = fmaxf(v, 0.f);
                C[(row0 + r) * ldc + col] = f2b(v);
            }
        }
    }
#undef STAGE_HT
#undef DSLOAD_A
#undef DSLOAD_B
#undef DOMFMA
#undef MIDBAR
#undef ENDBAR
}

// ---------------- extract v from qkv (bf16), transposed per head ----------------
__global__ __launch_bounds__(256) void split_v(const u16* __restrict__ qkv,
                                               u16* __restrict__ vT) {
    __shared__ u16 tile[32][33];
    int bh = blockIdx.z;
    int b = bh >> 4, h = bh & 15;
    int s0 = blockIdx.x * 32;
    int d0 = blockIdx.y * 32;
    int tx = threadIdx.x & 31, ty = threadIdx.x >> 5;
    for (int i = ty; i < 32; i += 8)
        tile[i][tx] = qkv[((long)(b * 512 + s0 + i)) * 3072 + 2048 + h * 64 + d0 + tx];
    __syncthreads();
    for (int i = ty; i < 32; i += 8)
        vT[((long)bh * 64 + d0 + i) * 512 + s0 + tx] = tile[tx][i];
}

// ---------------- fused attention: scores + mask + softmax + PV ----------------
// Unified 64-key-chunk pipeline over a shared double-buffered LDS tile used
// first for K (8 QK chunks) then for V (8 PV chunks). (Verified round 5.)
__global__ __launch_bounds__(256) void attn_fused(
    const u16* __restrict__ qkv, const u16* __restrict__ vT,
    const int* __restrict__ mask, float* __restrict__ attnOut,
    u16* __restrict__ ctx) {
    __shared__ __align__(16) u16 s_k[2][64][72];      // K/V chunk staging (dbuf)
    __shared__ __align__(16) u16 s_p[4][16][68];      // per-wave P chunk (A-layout)
    __shared__ unsigned long long m_bits[8];

    // XCD-aware decode: xcd = id&7 owns bh === xcd (mod 8)
    int id = blockIdx.x;
    int t_ = id >> 3;
    int mtile = t_ & 7;
    int bh = (id & 7) + ((t_ >> 3) << 3);
    int b = bh >> 4, h = bh & 15;
    int tid = threadIdx.x, lane = tid & 63, wave = tid >> 6;
    int lrow = lane & 15, quad = lane >> 4;
    int m0 = mtile * 64;

    const u16* Qbase = qkv + (long)(b * 512) * 3072 + h * 64;
    const u16* Kbase = Qbase + 1024;
    const u16* vh = vT + (long)bh * 64 * 512;

    {   // mask bitmask: bit j of m_bits[c] = (mask[b*512 + c*64 + j] != 0)
        int i0 = wave * 64 + lane;
        unsigned long long bl0 = __ballot(mask[b * 512 + i0] != 0);
        if (lane == 0) m_bits[wave] = bl0;
        unsigned long long bl1 = __ballot(mask[b * 512 + 256 + i0] != 0);
        if (lane == 0) m_bits[4 + wave] = bl1;
    }

    // stage Q tile [64][64] into s_k[0]; prefetch K chunk 0 into regs
    int sr = tid >> 3, sc = (tid & 7) * 8;        // this thread's staging slot
    int sr2 = (256 + tid) >> 3, sc2 = sc;         // second slot (rows 32..63)
    *(uint4*)&s_k[0][sr][sc]  = *(const uint4*)(Qbase + (long)(m0 + sr) * 3072 + sc);
    *(uint4*)&s_k[0][sr2][sc2] = *(const uint4*)(Qbase + (long)(m0 + sr2) * 3072 + sc2);
    uint4 kreg[2];
    kreg[0] = *(const uint4*)(Kbase + (long)sr * 3072 + sc);
    kreg[1] = *(const uint4*)(Kbase + (long)sr2 * 3072 + sc2);
    __syncthreads();
    bf16x8 qf[2];
    qf[0] = *(const bf16x8*)&s_k[0][wave * 16 + lrow][0 + quad * 8];
    qf[1] = *(const bf16x8*)&s_k[0][wave * 16 + lrow][32 + quad * 8];
    __syncthreads();   // all waves have Q fragments before chunk 0 overwrites s_k[0]

    f32x4 sacc[32];
#pragma unroll
    for (int t = 0; t < 32; t++) sacc[t] = (f32x4){0.f, 0.f, 0.f, 0.f};

    // S = Q K^T over 8 chunks of 64 key-rows; 1 barrier/chunk, dbuf overlap
    for (int nc = 0; nc < 8; nc++) {
        int buf = nc & 1;
        *(uint4*)&s_k[buf][sr][sc]  = kreg[0];
        *(uint4*)&s_k[buf][sr2][sc2] = kreg[1];
        if (nc < 7) {
            kreg[0] = *(const uint4*)(Kbase + (long)((nc + 1) * 64 + sr) * 3072 + sc);
            kreg[1] = *(const uint4*)(Kbase + (long)((nc + 1) * 64 + sr2) * 3072 + sc2);
        }
        __syncthreads();
#pragma unroll
        for (int ni = 0; ni < 4; ni++) {
            bf16x8 b0 = *(const bf16x8*)&s_k[buf][ni * 16 + lrow][0 + quad * 8];
            bf16x8 b1 = *(const bf16x8*)&s_k[buf][ni * 16 + lrow][32 + quad * 8];
            int t = nc * 4 + ni;
            sacc[t] = __builtin_amdgcn_mfma_f32_16x16x32_bf16(qf[0], b0, sacc[t], 0, 0, 0);
            sacc[t] = __builtin_amdgcn_mfma_f32_16x16x32_bf16(qf[1], b1, sacc[t], 0, 0, 0);
        }
    }

    // prefetch V chunk 0 (L2 latency hides under softmax VALU below)
    uint4 vreg[2];
    vreg[0] = *(const uint4*)(vh + (long)sr * 512 + sc);
    vreg[1] = *(const uint4*)(vh + (long)sr2 * 512 + sc2);

    // mask + scale; lane holds rows quad*4+r, cols t*16+lrow
    float mx[4] = {-3.0e38f, -3.0e38f, -3.0e38f, -3.0e38f};
#pragma unroll
    for (int t = 0; t < 32; t++) {
        int col = t * 16 + lrow;
        int on = (int)((m_bits[col >> 6] >> (col & 63)) & 1ull);
#pragma unroll
        for (int r = 0; r < 4; r++) {
            float s = on ? sacc[t][r] * 0.125f : -1e9f;
            sacc[t][r] = s;
            mx[r] = fmaxf(mx[r], s);
        }
    }
#pragma unroll
    for (int off = 1; off < 16; off <<= 1)
#pragma unroll
        for (int r = 0; r < 4; r++) mx[r] = fmaxf(mx[r], __shfl_xor(mx[r], off));
    float sm[4] = {0.f, 0.f, 0.f, 0.f};
#pragma unroll
    for (int t = 0; t < 32; t++)
#pragma unroll
        for (int r = 0; r < 4; r++) {
            float e = __expf(sacc[t][r] - mx[r]);
            sacc[t][r] = e;
            sm[r] += e;
        }
#pragma unroll
    for (int off = 1; off < 16; off <<= 1)
#pragma unroll
        for (int r = 0; r < 4; r++) sm[r] += __shfl_xor(sm[r], off);
#pragma unroll
    for (int r = 0; r < 4; r++) sm[r] = 1.0f / sm[r];
#pragma unroll
    for (int t = 0; t < 32; t++)
#pragma unroll
        for (int r = 0; r < 4; r++) sacc[t][r] *= sm[r];

    // PV over 8 chunks of 64 keys; V staged through the same dbuf, 1 barrier/chunk.
    f32x4 cacc[4];
#pragma unroll
    for (int ni = 0; ni < 4; ni++) cacc[ni] = (f32x4){0.f, 0.f, 0.f, 0.f};
    int prow = lane >> 4;      // row group for prob write
    int pseg = lane & 15;      // float4 index within 64-col chunk

    for (int nc = 0; nc < 8; nc++) {
        int buf = nc & 1;
        *(uint4*)&s_k[buf][sr][sc]  = vreg[0];
        *(uint4*)&s_k[buf][sr2][sc2] = vreg[1];
        if (nc < 7) {
            vreg[0] = *(const uint4*)(vh + (long)sr * 512 + (nc + 1) * 64 + sc);
            vreg[1] = *(const uint4*)(vh + (long)sr2 * 512 + (nc + 1) * 64 + sc2);
        }
        // transpose this wave's P chunk into s_p (wave-private, no barrier needed)
#pragma unroll
        for (int t2 = 0; t2 < 4; t2++) {
            int t = nc * 4 + t2;
#pragma unroll
            for (int r = 0; r < 4; r++)
                s_p[wave][quad * 4 + r][t2 * 16 + lrow] = f2b(sacc[t][r]);
        }
        __syncthreads();

        // coalesced probs write-out of this wave's 16x64 chunk
        {
            float* abase = attnOut + (long)bh * 512 * 512
                         + (long)(m0 + wave * 16) * 512 + nc * 64;
#pragma unroll
            for (int i = 0; i < 4; i++) {
                int row = i * 4 + prow;
                uint2 pv = *(const uint2*)&s_p[wave][row][pseg * 4];
                float4 o;
                o.x = b2f_u32(pv.x << 16);
                o.y = b2f_u32(pv.x & 0xffff0000u);
                o.z = b2f_u32(pv.y << 16);
                o.w = b2f_u32(pv.y & 0xffff0000u);
                *(float4*)(abase + (long)row * 512 + pseg * 4) = o;
            }
        }

#pragma unroll
        for (int kk = 0; kk < 2; kk++) {
            bf16x8 pf = *(const bf16x8*)&s_p[wave][lrow][kk * 32 + quad * 8];
#pragma unroll
            for (int ni = 0; ni < 4; ni++) {
                bf16x8 vf = *(const bf16x8*)&s_k[buf][ni * 16 + lrow][kk * 32 + quad * 8];
                cacc[ni] = __builtin_amdgcn_mfma_f32_16x16x32_bf16(pf, vf, cacc[ni], 0, 0, 0);
            }
        }
    }

    u16* crow = ctx + (long)(b * 512 + m0 + wave * 16 + quad * 4) * 1024 + h * 64 + lrow;
#pragma unroll
    for (int ni = 0; ni < 4; ni++)
#pragma unroll
        for (int r = 0; r < 4; r++) crow[(long)r * 1024 + ni * 16] = f2b(cacc[ni][r]);
}

// ---------------- out = LayerNorm(a + r) * g + beta ----------------
__global__ __launch_bounds__(256) void add_ln(const u16* __restrict__ a,
                                              const void* __restrict__ r, int r_fp32,
                                              const float* __restrict__ g,
                                              const float* __restrict__ beta,
                                              void* __restrict__ out, int out_fp32) {
    long row = blockIdx.x;
    const u16* pa = a + row * 1024;
    int tid = threadIdx.x;
    float v[4];
    float sum = 0.f, sq = 0.f;
#pragma unroll
    for (int j = 0; j < 4; j++) {
        int c = tid + j * 256;
        float rv = r_fp32 ? ((const float*)r)[row * 1024 + c]
                          : b2f(((const u16*)r)[row * 1024 + c]);
        float x = b2f(pa[c]) + rv;
        v[j] = x;
        sum += x;
        sq += x * x;
    }
#pragma unroll
    for (int off = 32; off >= 1; off >>= 1) {
        sum += __shfl_xor(sum, off);
        sq += __shfl_xor(sq, off);
    }
    __shared__ float red[2][4];
    int wave = tid >> 6, lane = tid & 63;
    if (lane == 0) { red[0][wave] = sum; red[1][wave] = sq; }
    __syncthreads();
    sum = red[0][0] + red[0][1] + red[0][2] + red[0][3];
    sq = red[1][0] + red[1][1] + red[1][2] + red[1][3];
    float mu = sum * (1.f / 1024.f);
    float var = sq * (1.f / 1024.f) - mu * mu;
    float rstd = rsqrtf(var + 1e-6f);
#pragma unroll
    for (int j = 0; j < 4; j++) {
        int c = tid + j * 256;
        float y = (v[j] - mu) * rstd * g[c] + beta[c];
        if (out_fp32) ((float*)out)[row * 1024 + c] = y;
        else ((u16*)out)[row * 1024 + c] = f2b(y);
    }
}

// ---------------- out = LayerNorm(a1 + a2 + colb + r) * g + beta (fp32 out) --------
// Combines split-K partials (a1,a2 fp32), column bias, and bf16 residual in one pass.
__global__ __launch_bounds__(256) void add_ln2(const float* __restrict__ a1,
                                               const float* __restrict__ a2,
                                               const float* __restrict__ colb,
                                               const u16* __restrict__ r,
                                               const float* __restrict__ g,
                                               const float* __restrict__ beta,
                                               float* __restrict__ out) {
    long row = blockIdx.x;
    int tid = threadIdx.x;
    float v[4];
    float sum = 0.f, sq = 0.f;
#pragma unroll
    for (int j = 0; j < 4; j++) {
        int c = tid + j * 256;
        float x = a1[row * 1024 + c] + a2[row * 1024 + c] + colb[c]
                + b2f(r[row * 1024 + c]);
        v[j] = x;
        sum += x;
        sq += x * x;
    }
#pragma unroll
    for (int off = 32; off >= 1; off >>= 1) {
        sum += __shfl_xor(sum, off);
        sq += __shfl_xor(sq, off);
    }
    __shared__ float red[2][4];
    int wave = tid >> 6, lane = tid & 63;
    if (lane == 0) { red[0][wave] = sum; red[1][wave] = sq; }
    __syncthreads();
    sum = red[0][0] + red[0][1] + red[0][2] + red[0][3];
    sq = red[1][0] + red[1][1] + red[1][2] + red[1][3];
    float mu = sum * (1.f / 1024.f);
    float var = sq * (1.f / 1024.f) - mu * mu;
    float rstd = rsqrtf(var + 1e-6f);
#pragma unroll
    for (int j = 0; j < 4; j++) {
        int c = tid + j * 256;
        out[row * 1024 + c] = (v[j] - mu) * rstd * g[c] + beta[c];
    }
}

extern "C" void kernel_launch(void* const* d_in, const int* in_sizes, int n_in,
                              void* d_out, int out_size, void* d_ws, size_t ws_size,
                              hipStream_t stream) {
    const float* x   = (const float*)d_in[0];
    const float* Wq  = (const float*)d_in[1];
    const float* bq  = (const float*)d_in[2];
    const float* Wk  = (const float*)d_in[3];
    const float* bk  = (const float*)d_in[4];
    const float* Wv  = (const float*)d_in[5];
    const float* bv  = (const float*)d_in[6];
    const float* Wo  = (const float*)d_in[7];
    const float* bo  = (const float*)d_in[8];
    const float* g1  = (const float*)d_in[9];
    const float* be1 = (const float*)d_in[10];
    const float* w1  = (const float*)d_in[11];
    const float* b1  = (const float*)d_in[12];
    const float* w2  = (const float*)d_in[13];
    const float* b2  = (const float*)d_in[14];
    const float* g2  = (const float*)d_in[15];
    const float* be2 = (const float*)d_in[16];
    const int* mask  = (const int*)d_in[17];

    float* out = (float*)d_out;                   // [8192][1024] fp32
    float* attn = out + (long)8192 * 1024;        // [256][512][512] fp32

    char* w = (char*)d_ws;
    auto alloc = [&](size_t bytes) {
        char* p = w;
        w += (bytes + 255) & ~(size_t)255;
        return p;
    };
    u16* WqkvT = (u16*)alloc(3072L * 1024 * 2);
    u16* WoT   = (u16*)alloc(1024L * 1024 * 2);
    u16* w1T   = (u16*)alloc(4096L * 1024 * 2);
    u16* w2T   = (u16*)alloc(1024L * 4096 * 2);
    float* bqkv = (float*)alloc(3072L * 4);
    u16* xb    = (u16*)alloc(8192L * 1024 * 2);
    char* P1 = alloc(8192L * 4096 * 2);  // qkv (48MB) -> ff (64MB)
    u16* qkv = (u16*)P1;
    u16* ff  = (u16*)P1;
    u16* vT  = (u16*)alloc(256L * 64 * 512 * 2);
    u16* ctx = (u16*)alloc(8192L * 1024 * 2);
    u16* x1  = (u16*)alloc(8192L * 1024 * 2);
    u16* y   = (u16*)alloc(8192L * 1024 * 2);
    float* y2p = (float*)alloc(2L * 8192 * 1024 * 4);  // split-K fp32 partials

    dim3 blk(256);

    transpose_f2b<<<dim3(32, 32), blk, 0, stream>>>(Wq, WqkvT, 1024, 1024);
    transpose_f2b<<<dim3(32, 32), blk, 0, stream>>>(Wk, WqkvT + 1024L * 1024, 1024, 1024);
    transpose_f2b<<<dim3(32, 32), blk, 0, stream>>>(Wv, WqkvT + 2048L * 1024, 1024, 1024);
    transpose_f2b<<<dim3(32, 32), blk, 0, stream>>>(Wo, WoT, 1024, 1024);
    transpose_f2b<<<dim3(128, 32), blk, 0, stream>>>(w1, w1T, 1024, 4096);
    transpose_f2b<<<dim3(32, 128), blk, 0, stream>>>(w2, w2T, 4096, 1024);
    concat3<<<12, blk, 0, stream>>>(bq, bk, bv, bqkv);
    conv_f2b<<<8192, blk, 0, stream>>>(x, xb, 8192L * 1024);

    // qkv = xb @ [Wq|Wk|Wv]^T + bqkv   (M=8192, N=3072, K=1024) — 256^2 8-phase
    gemm_bt256<<<dim3(384), dim3(512), 0, stream>>>(
        xb, WqkvT, bqkv, qkv, 8192, 3072, 1024, 1024, 1024, 3072, 0, 12);

    split_v<<<dim3(16, 2, 256), blk, 0, stream>>>(qkv, vT);

    // fused attention: probs -> attn (fp32), ctx (bf16 merged heads)
    attn_fused<<<dim3(2048), blk, 0, stream>>>(qkv, vT, mask, attn, ctx);

    // y = ctx @ Wo^T + bo   (M=8192, N=1024, K=1024) — 128x256 2-phase, 256 blocks
    gemm_btn<<<dim3(256), dim3(512), 0, stream>>>(
        ctx, WoT, bo, y, 1024, 1024, 1024, 1024, 0, 4);

    // x1 = LN(y + x)
    add_ln<<<8192, blk, 0, stream>>>(y, x, 1, g1, be1, x1, 0);

    // ff = relu(x1 @ w1^T + b1)   (M=8192, N=4096, K=1024) — 256^2 8-phase
    gemm_bt256<<<dim3(512), dim3(512), 0, stream>>>(
        x1, w1T, b1, ff, 8192, 4096, 1024, 1024, 1024, 4096, 1, 16);

    // y2 = ff @ w2^T (split-K=2, fp32 partials) — 256^2 8-phase, 256 blocks
    gemm_sk256<<<dim3(256), dim3(512), 0, stream>>>(
        ff, w2T, y2p, 2048, 4096, 4096, 1024, 4, 8192L * 1024);

    // out = LN(y2a + y2b + b2 + x1)
    add_ln2<<<8192, blk, 0, stream>>>(y2p, y2p + 8192L * 1024, b2, x1, g2, be2, out);
}

// Round 7
// 772.807 us; speedup vs baseline: 1.1258x; 1.0293x over previous
//
#include <hip/hip_runtime.h>
#include <hip/hip_bf16.h>

typedef unsigned short u16;
typedef __bf16 bf16x8 __attribute__((ext_vector_type(8)));
typedef float f32x4 __attribute__((ext_vector_type(4)));

static __device__ __forceinline__ float b2f(u16 x) {
    unsigned int u = ((unsigned int)x) << 16;
    float f; __builtin_memcpy(&f, &u, 4); return f;
}
static __device__ __forceinline__ float b2f_u32(unsigned int u) {
    float f; __builtin_memcpy(&f, &u, 4); return f;
}
static __device__ __forceinline__ u16 f2b(float f) {
    unsigned int u; __builtin_memcpy(&u, &f, 4);
    unsigned int lsb = (u >> 16) & 1u;
    u += 0x7fffu + lsb;
    return (u16)(u >> 16);
}

// async 16B global->LDS (wave-uniform LDS base + lane*16)
static __device__ __forceinline__ void gload16(const u16* g, u16* l) {
    __builtin_amdgcn_global_load_lds(
        (const __attribute__((address_space(1))) unsigned int*)g,
        (__attribute__((address_space(3))) unsigned int*)l, 16, 0, 0);
}

// ---------------- fused prep: 6 transposes + bias concat + x fp32->bf16 ------------
// One launch replaces 8 tiny kernels (saves ~7 inter-dispatch gaps).
static __device__ __forceinline__ void transpose_dev(const float* __restrict__ src,
                                                     u16* __restrict__ dst,
                                                     int R, int C, int bx, int by,
                                                     int tid, u16 (*tile)[33]) {
    int c0 = bx * 32, r0 = by * 32;
    int tx = tid & 31, ty = tid >> 5;
    for (int i = ty; i < 32; i += 8) {
        int r = r0 + i, c = c0 + tx;
        tile[i][tx] = (r < R && c < C) ? f2b(src[(long)r * C + c]) : (u16)0;
    }
    __syncthreads();
    for (int i = ty; i < 32; i += 8) {
        int c = c0 + i, r = r0 + tx;
        if (c < C && r < R) dst[(long)c * R + r] = tile[tx][i];
    }
}

__global__ __launch_bounds__(256) void prep(
    const float* __restrict__ Wq, const float* __restrict__ Wk,
    const float* __restrict__ Wv, const float* __restrict__ Wo,
    const float* __restrict__ w1, const float* __restrict__ w2,
    const float* __restrict__ bq, const float* __restrict__ bk,
    const float* __restrict__ bv,
    const float* __restrict__ x,
    u16* __restrict__ WqkvT, u16* __restrict__ WoT,
    u16* __restrict__ w1T, u16* __restrict__ w2T,
    float* __restrict__ bqkv, u16* __restrict__ xb) {
    __shared__ u16 tile[32][33];
    int id = blockIdx.x, tid = threadIdx.x;
    if (id < 4096) {            // Wq|Wk|Wv|Wo transposes, 1024 blocks each (32x32)
        int sec = id >> 10, t = id & 1023;
        const float* s = (sec == 0) ? Wq : (sec == 1) ? Wk : (sec == 2) ? Wv : Wo;
        u16* d = (sec == 3) ? WoT : WqkvT + (long)sec * 1024 * 1024;
        transpose_dev(s, d, 1024, 1024, t & 31, t >> 5, tid, tile);
    } else if (id < 8192) {     // w1 transpose, grid (128,32)
        int t = id - 4096;
        transpose_dev(w1, w1T, 1024, 4096, t % 128, t / 128, tid, tile);
    } else if (id < 12288) {    // w2 transpose, grid (32,128)
        int t = id - 8192;
        transpose_dev(w2, w2T, 4096, 1024, t & 31, t >> 5, tid, tile);
    } else if (id < 12300) {    // concat3
        int i = (id - 12288) * 256 + tid;
        if (i < 1024) bqkv[i] = bq[i];
        else if (i < 2048) bqkv[i] = bk[i - 1024];
        else if (i < 3072) bqkv[i] = bv[i - 2048];
    } else {                    // conv_f2b: 8192 blocks
        long i = ((long)(id - 12300) * 256 + tid) * 4;
        float4 f = *(const float4*)(x + i);
        ushort4 o;
        o.x = f2b(f.x); o.y = f2b(f.y); o.z = f2b(f.z); o.w = f2b(f.w);
        *(ushort4*)(xb + i) = o;
    }
}

// ---------------- 256x256 8-phase bt-GEMM (T2 swizzle + T3/T4 counted vmcnt + T5) ----
__global__ __launch_bounds__(512, 1) void gemm_bt256(
    const u16* __restrict__ A, const u16* __restrict__ B,
    const float* __restrict__ bias, u16* __restrict__ C,
    int M, int N, int K, int lda, int ldb, int ldc, int relu, int nbx) {
    __shared__ __align__(16) u16 lds[2][4][8192];

    int nwg = gridDim.x;
    int id = blockIdx.x;
    int swz = (id & 7) * (nwg >> 3) + (id >> 3);   // nwg % 8 == 0 at all call sites
    int bx = swz % nbx, by = swz / nbx;
    long m0 = (long)by * 256, n0 = (long)bx * 256;

    int tid = threadIdx.x, lane = tid & 63, wave = tid >> 6;
    int lrow = lane & 15, quad = lane >> 4;
    int wm2 = wave >> 2;        // M-half of wave (interleaved 16-row slabs)
    int wn2 = wave & 3;         // N-group of wave (interleaved 16-col slabs)

    int laneRd = (lrow * 64 + quad * 16) ^ (((lrow >> 3) & 1) << 5);
    int Sl = (lane * 16) ^ (((lane >> 5) & 1) << 5);
    int wr = (Sl >> 6) & 15;
    int wb = Sl & 63;

    f32x4 acc[8][4];
#pragma unroll
    for (int i = 0; i < 8; i++)
#pragma unroll
        for (int j = 0; j < 4; j++) acc[i][j] = (f32x4){0.f, 0.f, 0.f, 0.f};
    bf16x8 af[4][2], bfr[2][2];

#define STAGE_HT(nb, ht, kt) do {                                              \
    const char* _gb = ((ht) < 2)                                               \
        ? (const char*)(A + (m0 + (ht) * 128) * lda)                           \
        : (const char*)(B + (n0 + ((ht) - 2) * 128) * ldb);                    \
    long _ld = (long)(((ht) < 2) ? lda : ldb) * 2;                             \
    _Pragma("unroll")                                                          \
    for (int j = 0; j < 2; j++) {                                              \
        int sub = j * 8 + wave;                                                \
        int srow = (sub >> 1) * 16 + wr;                                       \
        int scolb = (sub & 1) * 64 + wb;                                       \
        gload16((const u16*)(_gb + (long)srow * _ld + (long)(kt) * 128 + scolb),\
                &lds[nb][ht][sub << 9]);                                       \
    }                                                                          \
} while (0)

#define DSLOAD_A(qm) do {                                                      \
    const char* _p = _ab + ((qm) << 14);                                       \
    _Pragma("unroll") for (int mi = 0; mi < 4; mi++)                           \
    _Pragma("unroll") for (int kk = 0; kk < 2; kk++)                           \
        af[mi][kk] = *(const bf16x8*)(_p + ((mi * 4 + kk) << 10));             \
} while (0)

#define DSLOAD_B(qn) do {                                                      \
    const char* _p = _bb + ((qn) << 14);                                       \
    _Pragma("unroll") for (int ni = 0; ni < 2; ni++)                           \
    _Pragma("unroll") for (int kk = 0; kk < 2; kk++)                           \
        bfr[ni][kk] = *(const bf16x8*)(_p + ((ni * 8 + kk) << 10));            \
} while (0)

#define DOMFMA(qm, qn) do {                                                    \
    __builtin_amdgcn_s_setprio(1);                                             \
    _Pragma("unroll") for (int mi = 0; mi < 4; mi++)                           \
    _Pragma("unroll") for (int ni = 0; ni < 2; ni++)                           \
    _Pragma("unroll") for (int kk = 0; kk < 2; kk++)                           \
        acc[(qm) * 4 + mi][(qn) * 2 + ni] =                                    \
            __builtin_amdgcn_mfma_f32_16x16x32_bf16(                           \
                af[mi][kk], bfr[ni][kk], acc[(qm) * 4 + mi][(qn) * 2 + ni],    \
                0, 0, 0);                                                      \
    __builtin_amdgcn_s_setprio(0);                                             \
} while (0)

#define MIDBAR()  do { __builtin_amdgcn_s_barrier(); __builtin_amdgcn_sched_barrier(0); } while (0)
#define ENDBAR()  do { __builtin_amdgcn_sched_barrier(0); __builtin_amdgcn_s_barrier(); } while (0)

    int NT = K >> 6;
    STAGE_HT(0, 0, 0);
    STAGE_HT(0, 2, 0);
    STAGE_HT(0, 1, 0);
    STAGE_HT(0, 3, 0);

    for (int t = 0; t < NT - 1; t++) {
        int cur = t & 1, nxt = cur ^ 1;
        const char* _ab = (const char*)&lds[cur][0][0] + (wm2 << 11) + laneRd;
        const char* _bb = (const char*)&lds[cur][2][0] + (wn2 << 11) + laneRd;
        STAGE_HT(nxt, 0, t + 1);
        asm volatile("s_waitcnt vmcnt(6)" ::: "memory");
        MIDBAR();
        DSLOAD_A(0); DSLOAD_B(0); DOMFMA(0, 0);
        ENDBAR();
        STAGE_HT(nxt, 2, t + 1);
        asm volatile("s_waitcnt vmcnt(6)" ::: "memory");
        MIDBAR();
        DSLOAD_A(1); DOMFMA(1, 0);
        ENDBAR();
        STAGE_HT(nxt, 1, t + 1);
        asm volatile("s_waitcnt vmcnt(6)" ::: "memory");
        MIDBAR();
        DSLOAD_B(1); DOMFMA(1, 1);
        ENDBAR();
        STAGE_HT(nxt, 3, t + 1);
        MIDBAR();
        DSLOAD_A(0); DOMFMA(0, 1);
        ENDBAR();
    }
    {   // tail tile: drain 4 -> 2 -> 0
        int cur = (NT - 1) & 1;
        const char* _ab = (const char*)&lds[cur][0][0] + (wm2 << 11) + laneRd;
        const char* _bb = (const char*)&lds[cur][2][0] + (wn2 << 11) + laneRd;
        asm volatile("s_waitcnt vmcnt(4)" ::: "memory");
        MIDBAR();
        DSLOAD_A(0); DSLOAD_B(0); DOMFMA(0, 0);
        ENDBAR();
        asm volatile("s_waitcnt vmcnt(2)" ::: "memory");
        MIDBAR();
        DSLOAD_A(1); DOMFMA(1, 0);
        ENDBAR();
        asm volatile("s_waitcnt vmcnt(0)" ::: "memory");
        MIDBAR();
        DSLOAD_B(1); DOMFMA(1, 1);
        ENDBAR();
        DSLOAD_A(0); DOMFMA(0, 1);
    }

#pragma unroll
    for (int mg = 0; mg < 8; mg++) {
        long row0 = m0 + (long)(((mg >> 2) * 8 + (mg & 3) * 2 + wm2) * 16 + quad * 4);
#pragma unroll
        for (int ng = 0; ng < 4; ng++) {
            long col = n0 + ((ng >> 1) * 8 + (ng & 1) * 4 + wn2) * 16 + lrow;
            float bv = bias ? bias[col] : 0.f;
#pragma unroll
            for (int r = 0; r < 4; r++) {
                float v = acc[mg][ng][r] + bv;
                if (relu) v = fmaxf(v, 0.f);
                C[(row0 + r) * ldc + col] = f2b(v);
            }
        }
    }
#undef STAGE_HT
#undef DSLOAD_A
#undef DSLOAD_B
#undef DOMFMA
}

// ---------------- split-K=2 256x256 8-phase bt-GEMM, fp32 partial output -----------
__global__ __launch_bounds__(512, 1) void gemm_sk256(
    const u16* __restrict__ A, const u16* __restrict__ B,
    float* __restrict__ Cf,
    int Ksplit, int lda, int ldb, int ldc, int nbx, long csize) {
    __shared__ __align__(16) u16 lds[2][4][8192];

    int id = blockIdx.x;
    int sp = id & 1;
    int id2 = id >> 1;
    int nwg2 = gridDim.x >> 1;
    int swz = (id2 & 7) * (nwg2 >> 3) + (id2 >> 3);
    int bx = swz % nbx, by = swz / nbx;
    long m0 = (long)by * 256, n0 = (long)bx * 256;

    A += (long)sp * Ksplit;
    B += (long)sp * Ksplit;
    Cf += (long)sp * csize;

    int tid = threadIdx.x, lane = tid & 63, wave = tid >> 6;
    int lrow = lane & 15, quad = lane >> 4;
    int wm2 = wave >> 2;
    int wn2 = wave & 3;

    int laneRd = (lrow * 64 + quad * 16) ^ (((lrow >> 3) & 1) << 5);
    int Sl = (lane * 16) ^ (((lane >> 5) & 1) << 5);
    int wr = (Sl >> 6) & 15;
    int wb = Sl & 63;

    f32x4 acc[8][4];
#pragma unroll
    for (int i = 0; i < 8; i++)
#pragma unroll
        for (int j = 0; j < 4; j++) acc[i][j] = (f32x4){0.f, 0.f, 0.f, 0.f};
    bf16x8 af[4][2], bfr[2][2];

#define STAGE_HT(nb, ht, kt) do {                                              \
    const char* _gb = ((ht) < 2)                                               \
        ? (const char*)(A + (m0 + (ht) * 128) * lda)                           \
        : (const char*)(B + (n0 + ((ht) - 2) * 128) * ldb);                    \
    long _ld = (long)(((ht) < 2) ? lda : ldb) * 2;                             \
    _Pragma("unroll")                                                          \
    for (int j = 0; j < 2; j++) {                                              \
        int sub = j * 8 + wave;                                                \
        int srow = (sub >> 1) * 16 + wr;                                       \
        int scolb = (sub & 1) * 64 + wb;                                       \
        gload16((const u16*)(_gb + (long)srow * _ld + (long)(kt) * 128 + scolb),\
                &lds[nb][ht][sub << 9]);                                       \
    }                                                                          \
} while (0)

#define DSLOAD_A(qm) do {                                                      \
    const char* _p = _ab + ((qm) << 14);                                       \
    _Pragma("unroll") for (int mi = 0; mi < 4; mi++)                           \
    _Pragma("unroll") for (int kk = 0; kk < 2; kk++)                           \
        af[mi][kk] = *(const bf16x8*)(_p + ((mi * 4 + kk) << 10));             \
} while (0)

#define DSLOAD_B(qn) do {                                                      \
    const char* _p = _bb + ((qn) << 14);                                       \
    _Pragma("unroll") for (int ni = 0; ni < 2; ni++)                           \
    _Pragma("unroll") for (int kk = 0; kk < 2; kk++)                           \
        bfr[ni][kk] = *(const bf16x8*)(_p + ((ni * 8 + kk) << 10));            \
} while (0)

#define DOMFMA(qm, qn) do {                                                    \
    __builtin_amdgcn_s_setprio(1);                                             \
    _Pragma("unroll") for (int mi = 0; mi < 4; mi++)                           \
    _Pragma("unroll") for (int ni = 0; ni < 2; ni++)                           \
    _Pragma("unroll") for (int kk = 0; kk < 2; kk++)                           \
        acc[(qm) * 4 + mi][(qn) * 2 + ni] =                                    \
            __builtin_amdgcn_mfma_f32_16x16x32_bf16(                           \
                af[mi][kk], bfr[ni][kk], acc[(qm) * 4 + mi][(qn) * 2 + ni],    \
                0, 0, 0);                                                      \
    __builtin_amdgcn_s_setprio(0);                                             \
} while (0)

    int NT = Ksplit >> 6;
    STAGE_HT(0, 0, 0);
    STAGE_HT(0, 2, 0);
    STAGE_HT(0, 1, 0);
    STAGE_HT(0, 3, 0);

    for (int t = 0; t < NT - 1; t++) {
        int cur = t & 1, nxt = cur ^ 1;
        const char* _ab = (const char*)&lds[cur][0][0] + (wm2 << 11) + laneRd;
        const char* _bb = (const char*)&lds[cur][2][0] + (wn2 << 11) + laneRd;
        STAGE_HT(nxt, 0, t + 1);
        asm volatile("s_waitcnt vmcnt(6)" ::: "memory");
        MIDBAR();
        DSLOAD_A(0); DSLOAD_B(0); DOMFMA(0, 0);
        ENDBAR();
        STAGE_HT(nxt, 2, t + 1);
        asm volatile("s_waitcnt vmcnt(6)" ::: "memory");
        MIDBAR();
        DSLOAD_A(1); DOMFMA(1, 0);
        ENDBAR();
        STAGE_HT(nxt, 1, t + 1);
        asm volatile("s_waitcnt vmcnt(6)" ::: "memory");
        MIDBAR();
        DSLOAD_B(1); DOMFMA(1, 1);
        ENDBAR();
        STAGE_HT(nxt, 3, t + 1);
        MIDBAR();
        DSLOAD_A(0); DOMFMA(0, 1);
        ENDBAR();
    }
    {   // tail tile: drain 4 -> 2 -> 0
        int cur = (NT - 1) & 1;
        const char* _ab = (const char*)&lds[cur][0][0] + (wm2 << 11) + laneRd;
        const char* _bb = (const char*)&lds[cur][2][0] + (wn2 << 11) + laneRd;
        asm volatile("s_waitcnt vmcnt(4)" ::: "memory");
        MIDBAR();
        DSLOAD_A(0); DSLOAD_B(0); DOMFMA(0, 0);
        ENDBAR();
        asm volatile("s_waitcnt vmcnt(2)" ::: "memory");
        MIDBAR();
        DSLOAD_A(1); DOMFMA(1, 0);
        ENDBAR();
        asm volatile("s_waitcnt vmcnt(0)" ::: "memory");
        MIDBAR();
        DSLOAD_B(1); DOMFMA(1, 1);
        ENDBAR();
        DSLOAD_A(0); DOMFMA(0, 1);
    }

#pragma unroll
    for (int mg = 0; mg < 8; mg++) {
        long row0 = m0 + (long)(((mg >> 2) * 8 + (mg & 3) * 2 + wm2) * 16 + quad * 4);
#pragma unroll
        for (int ng = 0; ng < 4; ng++) {
            long col = n0 + ((ng >> 1) * 8 + (ng & 1) * 4 + wn2) * 16 + lrow;
#pragma unroll
            for (int r = 0; r < 4; r++)
                Cf[(row0 + r) * ldc + col] = acc[mg][ng][r];
        }
    }
#undef STAGE_HT
#undef DSLOAD_A
#undef DSLOAD_B
#undef DOMFMA
}

// ---------------- 128x256 2-phase counted-vmcnt bt-GEMM (for Wo) --------
__global__ __launch_bounds__(512, 1) void gemm_btn(
    const u16* __restrict__ A, const u16* __restrict__ B,
    const float* __restrict__ bias, u16* __restrict__ C,
    int K, int lda, int ldb, int ldc, int relu, int nbx) {
    __shared__ __align__(16) u16 lds[2][3][8192];

    int nwg = gridDim.x;
    int id = blockIdx.x;
    int swz = (id & 7) * (nwg >> 3) + (id >> 3);
    int bx = swz % nbx, by = swz / nbx;
    long m0 = (long)by * 128, n0 = (long)bx * 256;

    int tid = threadIdx.x, lane = tid & 63, wave = tid >> 6;
    int lrow = lane & 15, quad = lane >> 4;
    int wm2 = wave >> 2;
    int wn2 = wave & 3;

    int laneRd = (lrow * 64 + quad * 16) ^ (((lrow >> 3) & 1) << 5);
    int Sl = (lane * 16) ^ (((lane >> 5) & 1) << 5);
    int wr = (Sl >> 6) & 15;
    int wb = Sl & 63;

    f32x4 acc[4][4];
#pragma unroll
    for (int i = 0; i < 4; i++)
#pragma unroll
        for (int j = 0; j < 4; j++) acc[i][j] = (f32x4){0.f, 0.f, 0.f, 0.f};
    bf16x8 af[4][2], bfr[2][2];

#define STAGE_HT(nb, ht, kt) do {                                              \
    const char* _gb = ((ht) == 0)                                              \
        ? (const char*)(A + m0 * lda)                                          \
        : (const char*)(B + (n0 + ((ht) - 1) * 128) * ldb);                    \
    long _ld = (long)(((ht) == 0) ? lda : ldb) * 2;                            \
    _Pragma("unroll")                                                          \
    for (int j = 0; j < 2; j++) {                                              \
        int sub = j * 8 + wave;                                                \
        int srow = (sub >> 1) * 16 + wr;                                       \
        int scolb = (sub & 1) * 64 + wb;                                       \
        gload16((const u16*)(_gb + (long)srow * _ld + (long)(kt) * 128 + scolb),\
                &lds[nb][ht][sub << 9]);                                       \
    }                                                                          \
} while (0)

#define DSLOAD_A() do {                                                        \
    _Pragma("unroll") for (int mi = 0; mi < 4; mi++)                           \
    _Pragma("unroll") for (int kk = 0; kk < 2; kk++)                           \
        af[mi][kk] = *(const bf16x8*)(_ab + ((mi * 4 + kk) << 10));            \
} while (0)

#define DSLOAD_B(qn) do {                                                      \
    const char* _p = _b0 + (qn) * 16384;                                       \
    _Pragma("unroll") for (int ni = 0; ni < 2; ni++)                           \
    _Pragma("unroll") for (int kk = 0; kk < 2; kk++)                           \
        bfr[ni][kk] = *(const bf16x8*)(_p + ((ni * 8 + kk) << 10));            \
} while (0)

#define DOMFMA(qn) do {                                                        \
    __builtin_amdgcn_s_setprio(1);                                             \
    _Pragma("unroll") for (int mi = 0; mi < 4; mi++)                           \
    _Pragma("unroll") for (int ni = 0; ni < 2; ni++)                           \
    _Pragma("unroll") for (int kk = 0; kk < 2; kk++)                           \
        acc[mi][(qn) * 2 + ni] =                                               \
            __builtin_amdgcn_mfma_f32_16x16x32_bf16(                           \
                af[mi][kk], bfr[ni][kk], acc[mi][(qn) * 2 + ni], 0, 0, 0);     \
    __builtin_amdgcn_s_setprio(0);                                             \
} while (0)

    int NT = K >> 6;
    STAGE_HT(0, 0, 0);
    STAGE_HT(0, 1, 0);
    STAGE_HT(0, 2, 0);

    for (int t = 0; t < NT - 1; t++) {
        int cur = t & 1, nxt = cur ^ 1;
        const char* _ab = (const char*)&lds[cur][0][0] + (wm2 << 11) + laneRd;
        const char* _b0 = (const char*)&lds[cur][1][0] + (wn2 << 11) + laneRd;
        STAGE_HT(nxt, 0, t + 1);
        asm volatile("s_waitcnt vmcnt(4)" ::: "memory");
        MIDBAR();
        DSLOAD_A(); DSLOAD_B(0); DOMFMA(0);
        ENDBAR();
        STAGE_HT(nxt, 1, t + 1);
        STAGE_HT(nxt, 2, t + 1);
        asm volatile("s_waitcnt vmcnt(6)" ::: "memory");
        MIDBAR();
        DSLOAD_B(1); DOMFMA(1);
        ENDBAR();
    }
    {   // tail tile: drain 2 -> 0
        int cur = (NT - 1) & 1;
        const char* _ab = (const char*)&lds[cur][0][0] + (wm2 << 11) + laneRd;
        const char* _b0 = (const char*)&lds[cur][1][0] + (wn2 << 11) + laneRd;
        asm volatile("s_waitcnt vmcnt(2)" ::: "memory");
        MIDBAR();
        DSLOAD_A(); DSLOAD_B(0); DOMFMA(0);
        ENDBAR();
        asm volatile("s_waitcnt vmcnt(0)" ::: "memory");
        MIDBAR();
        DSLOAD_B(1); DOMFMA(1);
    }

#pragma unroll
    for (int mi = 0; mi < 4; mi++) {
        long row0 = m0 + (long)((mi * 2 + wm2) * 16 + quad * 4);
#pragma unroll
        for (int ng = 0; ng < 4; ng++) {
            long col = n0 + ((ng >> 1) * 8 + (ng & 1) * 4 + wn2) * 16 + lrow;
            float bv = bias ? bias[col] : 0.f;
#pragma unroll
            for (int r = 0; r < 4; r++) {
                float v = acc[mi][ng][r] + bv;
                if (relu) v = fmaxf(v, 0.f);
                C[(row0 + r) * ldc + col] = f2b(v);
            }
        }
    }
#undef STAGE_HT
#undef DSLOAD_A
#undef DSLOAD_B
#undef DOMFMA
#undef MIDBAR
#undef ENDBAR
}

// ---------------- extract v from qkv (bf16), transposed per head ----------------
__global__ __launch_bounds__(256) void split_v(const u16* __restrict__ qkv,
                                               u16* __restrict__ vT) {
    __shared__ u16 tile[32][33];
    int bh = blockIdx.z;
    int b = bh >> 4, h = bh & 15;
    int s0 = blockIdx.x * 32;
    int d0 = blockIdx.y * 32;
    int tx = threadIdx.x & 31, ty = threadIdx.x >> 5;
    for (int i = ty; i < 32; i += 8)
        tile[i][tx] = qkv[((long)(b * 512 + s0 + i)) * 3072 + 2048 + h * 64 + d0 + tx];
    __syncthreads();
    for (int i = ty; i < 32; i += 8)
        vT[((long)bh * 64 + d0 + i) * 512 + s0 + tx] = tile[tx][i];
}

// ---------------- fused attention: scores + mask + softmax + PV ----------------
// Unified 64-key-chunk pipeline (verified round 5). This round: PV MFMA cluster
// issued BEFORE the prob stores within each chunk (both read wave-private s_p;
// same-wave DS ops are in-order so no hazard) so stores overlap the MFMA chain.
__global__ __launch_bounds__(256) void attn_fused(
    const u16* __restrict__ qkv, const u16* __restrict__ vT,
    const int* __restrict__ mask, float* __restrict__ attnOut,
    u16* __restrict__ ctx) {
    __shared__ __align__(16) u16 s_k[2][64][72];      // K/V chunk staging (dbuf)
    __shared__ __align__(16) u16 s_p[4][16][68];      // per-wave P chunk (A-layout)
    __shared__ unsigned long long m_bits[8];

    // XCD-aware decode: xcd = id&7 owns bh === xcd (mod 8)
    int id = blockIdx.x;
    int t_ = id >> 3;
    int mtile = t_ & 7;
    int bh = (id & 7) + ((t_ >> 3) << 3);
    int b = bh >> 4, h = bh & 15;
    int tid = threadIdx.x, lane = tid & 63, wave = tid >> 6;
    int lrow = lane & 15, quad = lane >> 4;
    int m0 = mtile * 64;

    const u16* Qbase = qkv + (long)(b * 512) * 3072 + h * 64;
    const u16* Kbase = Qbase + 1024;
    const u16* vh = vT + (long)bh * 64 * 512;

    {   // mask bitmask: bit j of m_bits[c] = (mask[b*512 + c*64 + j] != 0)
        int i0 = wave * 64 + lane;
        unsigned long long bl0 = __ballot(mask[b * 512 + i0] != 0);
        if (lane == 0) m_bits[wave] = bl0;
        unsigned long long bl1 = __ballot(mask[b * 512 + 256 + i0] != 0);
        if (lane == 0) m_bits[4 + wave] = bl1;
    }

    // stage Q tile [64][64] into s_k[0]; prefetch K chunk 0 into regs
    int sr = tid >> 3, sc = (tid & 7) * 8;        // this thread's staging slot
    int sr2 = (256 + tid) >> 3, sc2 = sc;         // second slot (rows 32..63)
    *(uint4*)&s_k[0][sr][sc]  = *(const uint4*)(Qbase + (long)(m0 + sr) * 3072 + sc);
    *(uint4*)&s_k[0][sr2][sc2] = *(const uint4*)(Qbase + (long)(m0 + sr2) * 3072 + sc2);
    uint4 kreg[2];
    kreg[0] = *(const uint4*)(Kbase + (long)sr * 3072 + sc);
    kreg[1] = *(const uint4*)(Kbase + (long)sr2 * 3072 + sc2);
    __syncthreads();
    bf16x8 qf[2];
    qf[0] = *(const bf16x8*)&s_k[0][wave * 16 + lrow][0 + quad * 8];
    qf[1] = *(const bf16x8*)&s_k[0][wave * 16 + lrow][32 + quad * 8];
    __syncthreads();   // all waves have Q fragments before chunk 0 overwrites s_k[0]

    f32x4 sacc[32];
#pragma unroll
    for (int t = 0; t < 32; t++) sacc[t] = (f32x4){0.f, 0.f, 0.f, 0.f};

    // S = Q K^T over 8 chunks of 64 key-rows; 1 barrier/chunk, dbuf overlap
    for (int nc = 0; nc < 8; nc++) {
        int buf = nc & 1;
        *(uint4*)&s_k[buf][sr][sc]  = kreg[0];
        *(uint4*)&s_k[buf][sr2][sc2] = kreg[1];
        if (nc < 7) {
            kreg[0] = *(const uint4*)(Kbase + (long)((nc + 1) * 64 + sr) * 3072 + sc);
            kreg[1] = *(const uint4*)(Kbase + (long)((nc + 1) * 64 + sr2) * 3072 + sc2);
        }
        __syncthreads();
#pragma unroll
        for (int ni = 0; ni < 4; ni++) {
            bf16x8 b0 = *(const bf16x8*)&s_k[buf][ni * 16 + lrow][0 + quad * 8];
            bf16x8 b1 = *(const bf16x8*)&s_k[buf][ni * 16 + lrow][32 + quad * 8];
            int t = nc * 4 + ni;
            sacc[t] = __builtin_amdgcn_mfma_f32_16x16x32_bf16(qf[0], b0, sacc[t], 0, 0, 0);
            sacc[t] = __builtin_amdgcn_mfma_f32_16x16x32_bf16(qf[1], b1, sacc[t], 0, 0, 0);
        }
    }

    // prefetch V chunk 0 (L2 latency hides under softmax VALU below)
    uint4 vreg[2];
    vreg[0] = *(const uint4*)(vh + (long)sr * 512 + sc);
    vreg[1] = *(const uint4*)(vh + (long)sr2 * 512 + sc2);

    // mask + scale; lane holds rows quad*4+r, cols t*16+lrow
    float mx[4] = {-3.0e38f, -3.0e38f, -3.0e38f, -3.0e38f};
#pragma unroll
    for (int t = 0; t < 32; t++) {
        int col = t * 16 + lrow;
        int on = (int)((m_bits[col >> 6] >> (col & 63)) & 1ull);
#pragma unroll
        for (int r = 0; r < 4; r++) {
            float s = on ? sacc[t][r] * 0.125f : -1e9f;
            sacc[t][r] = s;
            mx[r] = fmaxf(mx[r], s);
        }
    }
#pragma unroll
    for (int off = 1; off < 16; off <<= 1)
#pragma unroll
        for (int r = 0; r < 4; r++) mx[r] = fmaxf(mx[r], __shfl_xor(mx[r], off));
    float sm[4] = {0.f, 0.f, 0.f, 0.f};
#pragma unroll
    for (int t = 0; t < 32; t++)
#pragma unroll
        for (int r = 0; r < 4; r++) {
            float e = __expf(sacc[t][r] - mx[r]);
            sacc[t][r] = e;
            sm[r] += e;
        }
#pragma unroll
    for (int off = 1; off < 16; off <<= 1)
#pragma unroll
        for (int r = 0; r < 4; r++) sm[r] += __shfl_xor(sm[r], off);
#pragma unroll
    for (int r = 0; r < 4; r++) sm[r] = 1.0f / sm[r];
#pragma unroll
    for (int t = 0; t < 32; t++)
#pragma unroll
        for (int r = 0; r < 4; r++) sacc[t][r] *= sm[r];

    // PV over 8 chunks of 64 keys; V staged through the same dbuf, 1 barrier/chunk.
    f32x4 cacc[4];
#pragma unroll
    for (int ni = 0; ni < 4; ni++) cacc[ni] = (f32x4){0.f, 0.f, 0.f, 0.f};
    int prow = lane >> 4;      // row group for prob write
    int pseg = lane & 15;      // float4 index within 64-col chunk

    for (int nc = 0; nc < 8; nc++) {
        int buf = nc & 1;
        *(uint4*)&s_k[buf][sr][sc]  = vreg[0];
        *(uint4*)&s_k[buf][sr2][sc2] = vreg[1];
        if (nc < 7) {
            vreg[0] = *(const uint4*)(vh + (long)sr * 512 + (nc + 1) * 64 + sc);
            vreg[1] = *(const uint4*)(vh + (long)sr2 * 512 + (nc + 1) * 64 + sc2);
        }
        // transpose this wave's P chunk into s_p (wave-private, no barrier needed)
#pragma unroll
        for (int t2 = 0; t2 < 4; t2++) {
            int t = nc * 4 + t2;
#pragma unroll
            for (int r = 0; r < 4; r++)
                s_p[wave][quad * 4 + r][t2 * 16 + lrow] = f2b(sacc[t][r]);
        }
        __syncthreads();

        // PV MFMA first: its LDS-read + MFMA chain overlaps the prob stores below
#pragma unroll
        for (int kk = 0; kk < 2; kk++) {
            bf16x8 pf = *(const bf16x8*)&s_p[wave][lrow][kk * 32 + quad * 8];
#pragma unroll
            for (int ni = 0; ni < 4; ni++) {
                bf16x8 vf = *(const bf16x8*)&s_k[buf][ni * 16 + lrow][kk * 32 + quad * 8];
                cacc[ni] = __builtin_amdgcn_mfma_f32_16x16x32_bf16(pf, vf, cacc[ni], 0, 0, 0);
            }
        }

        // coalesced probs write-out of this wave's 16x64 chunk
        {
            float* abase = attnOut + (long)bh * 512 * 512
                         + (long)(m0 + wave * 16) * 512 + nc * 64;
#pragma unroll
            for (int i = 0; i < 4; i++) {
                int row = i * 4 + prow;
                uint2 pv = *(const uint2*)&s_p[wave][row][pseg * 4];
                float4 o;
                o.x = b2f_u32(pv.x << 16);
                o.y = b2f_u32(pv.x & 0xffff0000u);
                o.z = b2f_u32(pv.y << 16);
                o.w = b2f_u32(pv.y & 0xffff0000u);
                *(float4*)(abase + (long)row * 512 + pseg * 4) = o;
            }
        }
    }

    u16* crow = ctx + (long)(b * 512 + m0 + wave * 16 + quad * 4) * 1024 + h * 64 + lrow;
#pragma unroll
    for (int ni = 0; ni < 4; ni++)
#pragma unroll
        for (int r = 0; r < 4; r++) crow[(long)r * 1024 + ni * 16] = f2b(cacc[ni][r]);
}

// ---------------- out = LayerNorm(a + r) * g + beta ----------------
__global__ __launch_bounds__(256) void add_ln(const u16* __restrict__ a,
                                              const void* __restrict__ r, int r_fp32,
                                              const float* __restrict__ g,
                                              const float* __restrict__ beta,
                                              void* __restrict__ out, int out_fp32) {
    long row = blockIdx.x;
    const u16* pa = a + row * 1024;
    int tid = threadIdx.x;
    float v[4];
    float sum = 0.f, sq = 0.f;
#pragma unroll
    for (int j = 0; j < 4; j++) {
        int c = tid + j * 256;
        float rv = r_fp32 ? ((const float*)r)[row * 1024 + c]
                          : b2f(((const u16*)r)[row * 1024 + c]);
        float x = b2f(pa[c]) + rv;
        v[j] = x;
        sum += x;
        sq += x * x;
    }
#pragma unroll
    for (int off = 32; off >= 1; off >>= 1) {
        sum += __shfl_xor(sum, off);
        sq += __shfl_xor(sq, off);
    }
    __shared__ float red[2][4];
    int wave = tid >> 6, lane = tid & 63;
    if (lane == 0) { red[0][wave] = sum; red[1][wave] = sq; }
    __syncthreads();
    sum = red[0][0] + red[0][1] + red[0][2] + red[0][3];
    sq = red[1][0] + red[1][1] + red[1][2] + red[1][3];
    float mu = sum * (1.f / 1024.f);
    float var = sq * (1.f / 1024.f) - mu * mu;
    float rstd = rsqrtf(var + 1e-6f);
#pragma unroll
    for (int j = 0; j < 4; j++) {
        int c = tid + j * 256;
        float y = (v[j] - mu) * rstd * g[c] + beta[c];
        if (out_fp32) ((float*)out)[row * 1024 + c] = y;
        else ((u16*)out)[row * 1024 + c] = f2b(y);
    }
}

// ---------------- out = LayerNorm(a1 + a2 + colb + r) * g + beta (fp32 out) --------
__global__ __launch_bounds__(256) void add_ln2(const float* __restrict__ a1,
                                               const float* __restrict__ a2,
                                               const float* __restrict__ colb,
                                               const u16* __restrict__ r,
                                               const float* __restrict__ g,
                                               const float* __restrict__ beta,
                                               float* __restrict__ out) {
    long row = blockIdx.x;
    int tid = threadIdx.x;
    float v[4];
    float sum = 0.f, sq = 0.f;
#pragma unroll
    for (int j = 0; j < 4; j++) {
        int c = tid + j * 256;
        float x = a1[row * 1024 + c] + a2[row * 1024 + c] + colb[c]
                + b2f(r[row * 1024 + c]);
        v[j] = x;
        sum += x;
        sq += x * x;
    }
#pragma unroll
    for (int off = 32; off >= 1; off >>= 1) {
        sum += __shfl_xor(sum, off);
        sq += __shfl_xor(sq, off);
    }
    __shared__ float red[2][4];
    int wave = tid >> 6, lane = tid & 63;
    if (lane == 0) { red[0][wave] = sum; red[1][wave] = sq; }
    __syncthreads();
    sum = red[0][0] + red[0][1] + red[0][2] + red[0][3];
    sq = red[1][0] + red[1][1] + red[1][2] + red[1][3];
    float mu = sum * (1.f / 1024.f);
    float var = sq * (1.f / 1024.f) - mu * mu;
    float rstd = rsqrtf(var + 1e-6f);
#pragma unroll
    for (int j = 0; j < 4; j++) {
        int c = tid + j * 256;
        out[row * 1024 + c] = (v[j] - mu) * rstd * g[c] + beta[c];
    }
}

extern "C" void kernel_launch(void* const* d_in, const int* in_sizes, int n_in,
                              void* d_out, int out_size, void* d_ws, size_t ws_size,
                              hipStream_t stream) {
    const float* x   = (const float*)d_in[0];
    const float* Wq  = (const float*)d_in[1];
    const float* bq  = (const float*)d_in[2];
    const float* Wk  = (const float*)d_in[3];
    const float* bk  = (const float*)d_in[4];
    const float* Wv  = (const float*)d_in[5];
    const float* bv  = (const float*)d_in[6];
    const float* Wo  = (const float*)d_in[7];
    const float* bo  = (const float*)d_in[8];
    const float* g1  = (const float*)d_in[9];
    const float* be1 = (const float*)d_in[10];
    const float* w1  = (const float*)d_in[11];
    const float* b1  = (const float*)d_in[12];
    const float* w2  = (const float*)d_in[13];
    const float* b2  = (const float*)d_in[14];
    const float* g2  = (const float*)d_in[15];
    const float* be2 = (const float*)d_in[16];
    const int* mask  = (const int*)d_in[17];

    float* out = (float*)d_out;                   // [8192][1024] fp32
    float* attn = out + (long)8192 * 1024;        // [256][512][512] fp32

    char* w = (char*)d_ws;
    auto alloc = [&](size_t bytes) {
        char* p = w;
        w += (bytes + 255) & ~(size_t)255;
        return p;
    };
    u16* WqkvT = (u16*)alloc(3072L * 1024 * 2);
    u16* WoT   = (u16*)alloc(1024L * 1024 * 2);
    u16* w1T   = (u16*)alloc(4096L * 1024 * 2);
    u16* w2T   = (u16*)alloc(1024L * 4096 * 2);
    float* bqkv = (float*)alloc(3072L * 4);
    u16* xb    = (u16*)alloc(8192L * 1024 * 2);
    char* P1 = alloc(8192L * 4096 * 2);  // qkv (48MB) -> ff (64MB)
    u16* qkv = (u16*)P1;
    u16* ff  = (u16*)P1;
    u16* vT  = (u16*)alloc(256L * 64 * 512 * 2);
    u16* ctx = (u16*)alloc(8192L * 1024 * 2);
    u16* x1  = (u16*)alloc(8192L * 1024 * 2);
    u16* y   = (u16*)alloc(8192L * 1024 * 2);
    float* y2p = (float*)alloc(2L * 8192 * 1024 * 4);  // split-K fp32 partials

    dim3 blk(256);

    // fused prep: all weight transposes + bias concat + x->bf16 in ONE launch
    prep<<<dim3(20492), blk, 0, stream>>>(
        Wq, Wk, Wv, Wo, w1, w2, bq, bk, bv, x,
        WqkvT, WoT, w1T, w2T, bqkv, xb);

    // qkv = xb @ [Wq|Wk|Wv]^T + bqkv   (M=8192, N=3072, K=1024) — 256^2 8-phase
    gemm_bt256<<<dim3(384), dim3(512), 0, stream>>>(
        xb, WqkvT, bqkv, qkv, 8192, 3072, 1024, 1024, 1024, 3072, 0, 12);

    split_v<<<dim3(16, 2, 256), blk, 0, stream>>>(qkv, vT);

    // fused attention: probs -> attn (fp32), ctx (bf16 merged heads)
    attn_fused<<<dim3(2048), blk, 0, stream>>>(qkv, vT, mask, attn, ctx);

    // y = ctx @ Wo^T + bo   (M=8192, N=1024, K=1024) — 128x256 2-phase, 256 blocks
    gemm_btn<<<dim3(256), dim3(512), 0, stream>>>(
        ctx, WoT, bo, y, 1024, 1024, 1024, 1024, 0, 4);

    // x1 = LN(y + x)
    add_ln<<<8192, blk, 0, stream>>>(y, x, 1, g1, be1, x1, 0);

    // ff = relu(x1 @ w1^T + b1)   (M=8192, N=4096, K=1024) — 256^2 8-phase
    gemm_bt256<<<dim3(512), dim3(512), 0, stream>>>(
        x1, w1T, b1, ff, 8192, 4096, 1024, 1024, 1024, 4096, 1, 16);

    // y2 = ff @ w2^T (split-K=2, fp32 partials) — 256^2 8-phase, 256 blocks
    gemm_sk256<<<dim3(256), dim3(512), 0, stream>>>(
        ff, w2T, y2p, 2048, 4096, 4096, 1024, 4, 8192L * 1024);

    // out = LN(y2a + y2b + b2 + x1)
    add_ln2<<<8192, blk, 0, stream>>>(y2p, y2p + 8192L * 1024, b2, x1, g2, be2, out);
}